// Round 5
// baseline (726.043 us; speedup 1.0000x reference)
//
#include <hip/hip_runtime.h>

#define NN 20000
#define NE 640000
#define NET (NE + NN)   // 660000 edges incl. self-loops
#define NB 128          // CSR range-partition blocks
#define RR 157          // ceil(NN/NB)

typedef __attribute__((ext_vector_type(8))) short bf16x8;
typedef __attribute__((ext_vector_type(4))) float f32x4;

__device__ inline ushort f2bf_rne(float x) {
    unsigned u = __float_as_uint(x);
    return (ushort)((u + 0x7FFFu + ((u >> 16) & 1u)) >> 16);
}
__device__ inline float bf2f(ushort u) {
    return __uint_as_float(((unsigned)u) << 16);
}
__device__ inline void split2(float x, ushort& hi, ushort& lo) {
    unsigned u = __float_as_uint(x);
    unsigned r = (u + 0x7FFFu + ((u >> 16) & 1u)) & 0xFFFF0000u;  // RNE to bf16
    hi = (ushort)(r >> 16);
    lo = f2bf_rne(x - __uint_as_float(r));   // x - hi is exact
}

// ---------------- pre1: range-partitioned degree histogram + folds ----------------
__global__ void pre1_kernel(const int* __restrict__ ei, int* __restrict__ deg,
                            int* __restrict__ rsum,
                            const float* __restrict__ W1, const float* __restrict__ as1,
                            const float* __restrict__ ad1, float* __restrict__ w1f,
                            const float* __restrict__ W2, const float* __restrict__ as2,
                            const float* __restrict__ ad2, float* __restrict__ w2f) {
    int b = blockIdx.x, t = threadIdx.x;
    if (b < NB) {
        __shared__ int hist[RR];
        __shared__ int wred[4];
        int lo = b * RR;
        int Ra = min(RR, NN - lo);
        for (int i = t; i < Ra; i += 256) hist[i] = 0;
        __syncthreads();
        const int4* d4 = (const int4*)(ei + NE);
        for (int e4 = t; e4 < NE / 4; e4 += 256) {
            int4 d = d4[e4];
            unsigned a;
            a = (unsigned)(d.x - lo); if (a < (unsigned)Ra) atomicAdd(&hist[a], 1);
            a = (unsigned)(d.y - lo); if (a < (unsigned)Ra) atomicAdd(&hist[a], 1);
            a = (unsigned)(d.z - lo); if (a < (unsigned)Ra) atomicAdd(&hist[a], 1);
            a = (unsigned)(d.w - lo); if (a < (unsigned)Ra) atomicAdd(&hist[a], 1);
        }
        __syncthreads();
        int part = 0;
        for (int i = t; i < Ra; i += 256) {
            int v = hist[i] + 1;   // +1 self-loop
            deg[lo + i] = v;
            part += v;
        }
#pragma unroll
        for (int o = 32; o > 0; o >>= 1) part += __shfl_xor(part, o, 64);
        if ((t & 63) == 0) wred[t >> 6] = part;
        __syncthreads();
        if (t == 0) rsum[b] = wred[0] + wred[1] + wred[2] + wred[3];
    } else if (b == NB) {
        if (t < 128) {
            int k = t;
#pragma unroll
            for (int h = 0; h < 4; h++) {
                float s1 = 0.f, s2 = 0.f;
                for (int c = 0; c < 64; c++) {
                    float w = W1[k * 256 + h * 64 + c];
                    s1 += w * as1[h * 64 + c];
                    s2 += w * ad1[h * 64 + c];
                }
                w1f[k * 8 + h] = s1;
                w1f[k * 8 + 4 + h] = s2;
            }
        }
    } else {
        int k = t;  // 256
        float s1 = 0.f, s2 = 0.f;
        for (int c = 0; c < 128; c++) {
            float w = W2[k * 128 + c];
            s1 += w * as2[c];
            s2 += w * ad2[c];
        }
        w2f[k * 2] = s1;
        w2f[k * 2 + 1] = s2;
    }
}

// ---------------- tiny scan over NB range sums ----------------
__global__ void scan_small(const int* __restrict__ rsum, int* __restrict__ rbase) {
    int t = threadIdx.x;  // 64
    int carry = 0;
#pragma unroll
    for (int c = 0; c < NB / 64; c++) {
        int i = c * 64 + t;
        int v = rsum[i];
        int s = v;
#pragma unroll
        for (int o = 1; o < 64; o <<= 1) { int u = __shfl_up(s, o, 64); if (t >= o) s += u; }
        rbase[i] = carry + s - v;
        carry += __shfl(s, 63, 64);
    }
}

// ---------------- pre2: range-partitioned CSR fill + alar_cast ----------------
__global__ void pre2_kernel(const int* __restrict__ ei, const int* __restrict__ deg,
                            const int* __restrict__ rbase, int* __restrict__ offs,
                            int* __restrict__ csr_src, const float* __restrict__ X,
                            const float* __restrict__ wf, ushort* __restrict__ Xbf,
                            float* __restrict__ al, float* __restrict__ ar) {
    int b = blockIdx.x, t = threadIdx.x;
    if (b < NB) {
        __shared__ int lcur[RR];
        int lo = b * RR;
        int Ra = min(RR, NN - lo);
        if (t < 64) {
            int rb = rbase[b];
            int carry = 0;
#pragma unroll
            for (int c = 0; c < 3; c++) {
                int i = c * 64 + t;
                int v = (i < Ra) ? deg[lo + i] : 0;
                int s = v;
#pragma unroll
                for (int o = 1; o < 64; o <<= 1) { int u = __shfl_up(s, o, 64); if (t >= o) s += u; }
                if (i < Ra) {
                    int off = rb + carry + s - v;
                    offs[lo + i] = off;
                    lcur[i] = off;
                }
                carry += __shfl(s, 63, 64);
            }
        }
        if (b == 0 && t == 255) offs[NN] = NET;
        __syncthreads();
        const int4* d4 = (const int4*)(ei + NE);
        for (int e4 = t; e4 < NE / 4; e4 += 256) {
            int4 d = d4[e4];
            int e = e4 * 4;
            unsigned a;
            a = (unsigned)(d.x - lo); if (a < (unsigned)Ra) { int p = atomicAdd(&lcur[a], 1); csr_src[p] = ei[e]; }
            a = (unsigned)(d.y - lo); if (a < (unsigned)Ra) { int p = atomicAdd(&lcur[a], 1); csr_src[p] = ei[e + 1]; }
            a = (unsigned)(d.z - lo); if (a < (unsigned)Ra) { int p = atomicAdd(&lcur[a], 1); csr_src[p] = ei[e + 2]; }
            a = (unsigned)(d.w - lo); if (a < (unsigned)Ra) { int p = atomicAdd(&lcur[a], 1); csr_src[p] = ei[e + 3]; }
        }
        __syncthreads();
        for (int i = t; i < Ra; i += 256) csr_src[lcur[i]] = lo + i;  // self-loop in last slot
    } else {
        __shared__ float ws[8][128];
        for (int i = t; i < 1024; i += 256) ws[i & 7][i >> 3] = wf[i];
        __syncthreads();
        int wv = t >> 6, ln = t & 63;
        int n = (b - NB) * 4 + wv;
        float2 xv = *(const float2*)(X + (size_t)n * 128 + ln * 2);
        ushort2 ub;
        ub.x = f2bf_rne(xv.x);
        ub.y = f2bf_rne(xv.y);
        *(ushort2*)(Xbf + (size_t)n * 128 + ln * 2) = ub;
        float p[8];
#pragma unroll
        for (int o = 0; o < 8; o++) p[o] = xv.x * ws[o][ln * 2] + xv.y * ws[o][ln * 2 + 1];
#pragma unroll
        for (int off = 32; off > 0; off >>= 1)
#pragma unroll
            for (int o = 0; o < 8; o++) p[o] += __shfl_xor(p[o], off, 64);
        if (ln == 0) {
#pragma unroll
            for (int h = 0; h < 4; h++) {
                al[n * 4 + h] = p[h];
                ar[n * 4 + h] = p[4 + h];
            }
        }
    }
}

// ---------------- layer-2 al/ar = x1 @ w2f ----------------
__launch_bounds__(256)
__global__ void alar_apply2(const float* __restrict__ X, const float* __restrict__ wf,
                            float* __restrict__ al, float* __restrict__ ar) {
    __shared__ float ws[2][256];
    int t = threadIdx.x;
    for (int i = t; i < 512; i += 256) ws[i & 1][i >> 1] = wf[i];
    __syncthreads();
    int wv = t >> 6, ln = t & 63;
    int n = blockIdx.x * 4 + wv;
    float p0 = 0.f, p1 = 0.f;
#pragma unroll
    for (int cc = 0; cc < 4; cc++) {
        int c = ln * 4 + cc;
        float x = X[(size_t)n * 256 + c];
        p0 += x * ws[0][c];
        p1 += x * ws[1][c];
    }
#pragma unroll
    for (int off = 32; off > 0; off >>= 1) {
        p0 += __shfl_xor(p0, off, 64);
        p1 += __shfl_xor(p1, off, 64);
    }
    if (ln == 0) { al[n] = p0; ar[n] = p1; }
}

// ---------------- GAT gather: half-wave per node, register-only softmax ----------------
template <int H, bool FUSE>
__launch_bounds__(256)
__global__ void gat_gather_w(const ushort* __restrict__ X, const float* __restrict__ al,
                             const float* __restrict__ ar, const int* __restrict__ offs,
                             const int* __restrict__ csr, const float* __restrict__ bias,
                             void* __restrict__ outp) {
    int t = threadIdx.x;
    int wv = t >> 6, ln = t & 63;
    int hw = ln >> 5, l32 = ln & 31;
    int n = blockIdx.x * 8 + wv * 2 + hw;
    int e0 = offs[n], e1 = offs[n + 1];

    float arv[H], m[H], srun[H], acc[4][H];
#pragma unroll
    for (int h = 0; h < H; h++) {
        arv[h] = ar[n * H + h];
        m[h] = -1e30f; srun[h] = 0.f;
#pragma unroll
        for (int c = 0; c < 4; c++) acc[c][h] = 0.f;
    }
    const ushort* Xc = X + (size_t)l32 * 4;

    for (int base = e0; base < e1; base += 64) {
        int cnt = e1 - base; if (cnt > 64) cnt = 64;
        bool vA = l32 < cnt, vB = l32 + 32 < cnt;
        int srcA = 0, srcB = 0;
        float wA[H], wB[H], lmx[H];
#pragma unroll
        for (int h = 0; h < H; h++) { lmx[h] = -1e30f; wA[h] = 0.f; wB[h] = 0.f; }
        if (vA) {
            srcA = csr[base + l32];
            float av[H];
            if (H == 4) {
                float4 a4 = *(const float4*)(al + (size_t)srcA * 4);
                av[0] = a4.x; av[H > 1 ? 1 : 0] = a4.y;
                av[H > 2 ? 2 : 0] = a4.z; av[H > 3 ? 3 : 0] = a4.w;
            } else {
                av[0] = al[srcA];
            }
#pragma unroll
            for (int h = 0; h < H; h++) {
                float lg = av[h] + arv[h];
                lg = lg > 0.f ? lg : 0.2f * lg;
                wA[h] = lg;
                lmx[h] = fmaxf(lmx[h], lg);
            }
        }
        if (vB) {
            srcB = csr[base + l32 + 32];
            float av[H];
            if (H == 4) {
                float4 a4 = *(const float4*)(al + (size_t)srcB * 4);
                av[0] = a4.x; av[H > 1 ? 1 : 0] = a4.y;
                av[H > 2 ? 2 : 0] = a4.z; av[H > 3 ? 3 : 0] = a4.w;
            } else {
                av[0] = al[srcB];
            }
#pragma unroll
            for (int h = 0; h < H; h++) {
                float lg = av[h] + arv[h];
                lg = lg > 0.f ? lg : 0.2f * lg;
                wB[h] = lg;
                lmx[h] = fmaxf(lmx[h], lg);
            }
        }
#pragma unroll
        for (int off = 16; off > 0; off >>= 1)
#pragma unroll
            for (int h = 0; h < H; h++) lmx[h] = fmaxf(lmx[h], __shfl_xor(lmx[h], off, 32));
        float ls[H];
#pragma unroll
        for (int h = 0; h < H; h++) {
            float mn = fmaxf(m[h], lmx[h]);
            float sc = __expf(m[h] - mn);
            m[h] = mn;
            srun[h] *= sc;
#pragma unroll
            for (int c = 0; c < 4; c++) acc[c][h] *= sc;
            float a = vA ? __expf(wA[h] - mn) : 0.f;
            float b = vB ? __expf(wB[h] - mn) : 0.f;
            wA[h] = a; wB[h] = b;
            ls[h] = a + b;
        }
#pragma unroll
        for (int off = 16; off > 0; off >>= 1)
#pragma unroll
            for (int h = 0; h < H; h++) ls[h] += __shfl_xor(ls[h], off, 32);
#pragma unroll
        for (int h = 0; h < H; h++) srun[h] += ls[h];

        int k = 0;
        for (; k + 4 <= cnt; k += 4) {
            int r4[4]; float w4[4][H];
            if (k < 32) {
#pragma unroll
                for (int q = 0; q < 4; q++) {
                    r4[q] = __shfl(srcA, k + q, 32);
#pragma unroll
                    for (int h = 0; h < H; h++) w4[q][h] = __shfl(wA[h], k + q, 32);
                }
            } else {
#pragma unroll
                for (int q = 0; q < 4; q++) {
                    r4[q] = __shfl(srcB, k - 32 + q, 32);
#pragma unroll
                    for (int h = 0; h < H; h++) w4[q][h] = __shfl(wB[h], k - 32 + q, 32);
                }
            }
            uint2 u[4];
#pragma unroll
            for (int q = 0; q < 4; q++) u[q] = *(const uint2*)(Xc + (size_t)r4[q] * 128);
#pragma unroll
            for (int q = 0; q < 4; q++) {
                float x0 = __uint_as_float(u[q].x << 16);
                float x1 = __uint_as_float(u[q].x & 0xffff0000u);
                float x2 = __uint_as_float(u[q].y << 16);
                float x3 = __uint_as_float(u[q].y & 0xffff0000u);
#pragma unroll
                for (int h = 0; h < H; h++) {
                    acc[0][h] = fmaf(w4[q][h], x0, acc[0][h]);
                    acc[1][h] = fmaf(w4[q][h], x1, acc[1][h]);
                    acc[2][h] = fmaf(w4[q][h], x2, acc[2][h]);
                    acc[3][h] = fmaf(w4[q][h], x3, acc[3][h]);
                }
            }
        }
        for (; k < cnt; k++) {
            int r; float wk[H];
            if (k < 32) {
                r = __shfl(srcA, k, 32);
#pragma unroll
                for (int h = 0; h < H; h++) wk[h] = __shfl(wA[h], k, 32);
            } else {
                r = __shfl(srcB, k - 32, 32);
#pragma unroll
                for (int h = 0; h < H; h++) wk[h] = __shfl(wB[h], k - 32, 32);
            }
            uint2 u = *(const uint2*)(Xc + (size_t)r * 128);
            float x0 = __uint_as_float(u.x << 16);
            float x1 = __uint_as_float(u.x & 0xffff0000u);
            float x2 = __uint_as_float(u.y << 16);
            float x3 = __uint_as_float(u.y & 0xffff0000u);
#pragma unroll
            for (int h = 0; h < H; h++) {
                acc[0][h] = fmaf(wk[h], x0, acc[0][h]);
                acc[1][h] = fmaf(wk[h], x1, acc[1][h]);
                acc[2][h] = fmaf(wk[h], x2, acc[2][h]);
                acc[3][h] = fmaf(wk[h], x3, acc[3][h]);
            }
        }
    }
    if (FUSE) {
        float* out = (float*)outp;
        float inv = 1.f / srun[0];
        const float* bp = bias + l32 * 4;
        float4 o;
        float v0 = acc[0][0] * inv + bp[0];
        float v1 = acc[1][0] * inv + bp[1];
        float v2 = acc[2][0] * inv + bp[2];
        float v3 = acc[3][0] * inv + bp[3];
        o.x = v0 > 0.f ? v0 : __expf(v0) - 1.f;
        o.y = v1 > 0.f ? v1 : __expf(v1) - 1.f;
        o.z = v2 > 0.f ? v2 : __expf(v2) - 1.f;
        o.w = v3 > 0.f ? v3 : __expf(v3) - 1.f;
        *(float4*)(out + (size_t)n * 128 + l32 * 4) = o;
    } else {
        ushort* out = (ushort*)outp;
#pragma unroll
        for (int h = 0; h < H; h++) {
            float inv = 1.f / srun[h];
            ushort4 o = make_ushort4(f2bf_rne(acc[0][h] * inv), f2bf_rne(acc[1][h] * inv),
                                     f2bf_rne(acc[2][h] * inv), f2bf_rne(acc[3][h] * inv));
            *(ushort4*)(out + (size_t)n * (H * 128) + h * 128 + l32 * 4) = o;
        }
    }
}

// ---------------- MFMA split-bf16 GEMM ----------------
template <int ASPLIT, bool BT, int ACT, bool OUTBF, int BN>
__launch_bounds__(256)
__global__ void gemm3t(const void* __restrict__ Aptr, const float* __restrict__ B,
                       const float* __restrict__ bias, void* __restrict__ Cptr,
                       int M, int K, int lda, int ldb, int ldc, int zA, int zB, int zC) {
    constexpr int NF = BN / 32;
    __shared__ ushort Ah[128 * 64];
    __shared__ ushort Al[ASPLIT ? 128 * 64 : 64];
    __shared__ ushort Bh[64 * BN];
    __shared__ ushort Bl[64 * BN];
    int tid = threadIdx.x;
    int z = blockIdx.z;
    int bm = blockIdx.x * 128;
    int ny = blockIdx.y * BN;
    int wid = tid >> 6, ln = tid & 63;
    int wm = wid >> 1, wn = wid & 1;
    f32x4 acc[4][NF];
#pragma unroll
    for (int a = 0; a < 4; a++)
#pragma unroll
        for (int b = 0; b < NF; b++)
#pragma unroll
            for (int j = 0; j < 4; j++) acc[a][b][j] = 0.f;
    const float* Af = (const float*)Aptr;
    const ushort* Au = (const ushort*)Aptr;
    size_t abase = (size_t)z * zA;
    int bcb = z * zB + ny;

    for (int k0 = 0; k0 < K; k0 += 64) {
#pragma unroll
        for (int i = 0; i < 8; i++) {
            int idx = tid + i * 256;
            int r = idx >> 4, c4 = (idx & 15) * 4;
            int gr = bm + r;
            int ab = (r * 128 + c4 * 2) ^ ((r & 7) << 4);
            if (ASPLIT) {
                float4 v = make_float4(0.f, 0.f, 0.f, 0.f);
                if (gr < M) v = *(const float4*)(Af + abase + (size_t)gr * lda + k0 + c4);
                ushort h0, h1, h2, h3, l0, l1, l2, l3;
                split2(v.x, h0, l0); split2(v.y, h1, l1);
                split2(v.z, h2, l2); split2(v.w, h3, l3);
                *(ushort4*)((char*)Ah + ab) = make_ushort4(h0, h1, h2, h3);
                *(ushort4*)((char*)Al + ab) = make_ushort4(l0, l1, l2, l3);
            } else {
                ushort4 v = make_ushort4(0, 0, 0, 0);
                if (gr < M) v = *(const ushort4*)(Au + abase + (size_t)gr * lda + k0 + c4);
                *(ushort4*)((char*)Ah + ab) = v;
            }
        }
        if (!BT) {
#pragma unroll
            for (int i = 0; i < BN / 16; i++) {
                int idx = tid + i * 256;
                int kk = idx / (BN / 4);
                int c4 = (idx % (BN / 4)) * 4;
                float4 v = *(const float4*)(B + (size_t)(k0 + kk) * ldb + bcb + c4);
                float vv[4] = {v.x, v.y, v.z, v.w};
#pragma unroll
                for (int q = 0; q < 4; q++) {
                    int nl = c4 + q;
                    int bb = (nl * 128 + kk * 2) ^ ((nl & 7) << 4);
                    ushort h, l;
                    split2(vv[q], h, l);
                    *(ushort*)((char*)Bh + bb) = h;
                    *(ushort*)((char*)Bl + bb) = l;
                }
            }
        } else {
#pragma unroll
            for (int i = 0; i < BN / 16; i++) {
                int idx = tid + i * 256;
                int nl = idx >> 4, k4 = (idx & 15) * 4;
                float4 v = *(const float4*)(B + (size_t)(ny + nl) * ldb + k0 + k4);
                ushort h0, h1, h2, h3, l0, l1, l2, l3;
                split2(v.x, h0, l0); split2(v.y, h1, l1);
                split2(v.z, h2, l2); split2(v.w, h3, l3);
                int bb = (nl * 128 + k4 * 2) ^ ((nl & 7) << 4);
                *(ushort4*)((char*)Bh + bb) = make_ushort4(h0, h1, h2, h3);
                *(ushort4*)((char*)Bl + bb) = make_ushort4(l0, l1, l2, l3);
            }
        }
        __syncthreads();
#pragma unroll
        for (int ks = 0; ks < 2; ks++) {
            int kb = ks * 64 + (ln >> 4) * 16;
            bf16x8 ah[4], alo[ASPLIT ? 4 : 1], bh[NF], bl[NF];
#pragma unroll
            for (int mf = 0; mf < 4; mf++) {
                int r = wm * 64 + mf * 16 + (ln & 15);
                int ab = (r * 128 + kb) ^ ((r & 7) << 4);
                ah[mf] = *(bf16x8*)((char*)Ah + ab);
                if (ASPLIT) alo[mf] = *(bf16x8*)((char*)Al + ab);
            }
#pragma unroll
            for (int nf = 0; nf < NF; nf++) {
                int nl = wn * (BN / 2) + nf * 16 + (ln & 15);
                int bb = (nl * 128 + kb) ^ ((nl & 7) << 4);
                bh[nf] = *(bf16x8*)((char*)Bh + bb);
                bl[nf] = *(bf16x8*)((char*)Bl + bb);
            }
#pragma unroll
            for (int mf = 0; mf < 4; mf++)
#pragma unroll
                for (int nf = 0; nf < NF; nf++) {
                    acc[mf][nf] = __builtin_amdgcn_mfma_f32_16x16x32_bf16(ah[mf], bh[nf], acc[mf][nf], 0, 0, 0);
                    acc[mf][nf] = __builtin_amdgcn_mfma_f32_16x16x32_bf16(ah[mf], bl[nf], acc[mf][nf], 0, 0, 0);
                    if (ASPLIT)
                        acc[mf][nf] = __builtin_amdgcn_mfma_f32_16x16x32_bf16(alo[mf], bh[nf], acc[mf][nf], 0, 0, 0);
                }
        }
        __syncthreads();
    }
    float* Cf = (float*)Cptr;
    ushort* Cu = (ushort*)Cptr;
#pragma unroll
    for (int mf = 0; mf < 4; mf++)
#pragma unroll
        for (int nf = 0; nf < NF; nf++) {
            int colL = ny + wn * (BN / 2) + nf * 16 + (ln & 15);
#pragma unroll
            for (int j = 0; j < 4; j++) {
                int row = bm + wm * 64 + mf * 16 + (ln >> 4) * 4 + j;
                if (row < M) {
                    float v = acc[mf][nf][j];
                    if (ACT) {
                        v += bias[z * zC + colL];
                        v = v > 0.f ? v : (__expf(v) - 1.f);
                    }
                    size_t ci = (size_t)row * ldc + z * zC + colL;
                    if (OUTBF) Cu[ci] = f2bf_rne(v);
                    else       Cf[ci] = v;
                }
            }
        }
}

// ---------------- GRU (h0=0) + heads + SIR physics ----------------
__launch_bounds__(128)
__global__ void gru_heads_kernel(const float* __restrict__ gi, const float* __restrict__ b_ih,
                                 const float* __restrict__ b_hh, const float* __restrict__ cI,
                                 const float* __restrict__ cR, const float* __restrict__ Npop,
                                 const float* __restrict__ I0, const float* __restrict__ R0,
                                 const float* __restrict__ W_I, const float* __restrict__ b_I,
                                 const float* __restrict__ W_R, const float* __restrict__ b_R,
                                 const float* __restrict__ W_sir, const float* __restrict__ b_sir,
                                 float* __restrict__ out_predI, float* __restrict__ out_predR,
                                 float* __restrict__ out_phyI, float* __restrict__ out_phyR,
                                 float* __restrict__ out_h) {
    int n = blockIdx.x, t = threadIdx.x;
    __shared__ float hc[130];
    __shared__ float s_pr[2];
    const float* g = gi + (size_t)n * 384;
    float ir = g[t] + b_ih[t];
    float iz = g[128 + t] + b_ih[128 + t];
    float ih = g[256 + t] + b_ih[256 + t];
    float r = 1.f / (1.f + expf(-(ir + b_hh[t])));
    float z = 1.f / (1.f + expf(-(iz + b_hh[128 + t])));
    float nn = tanhf(ih + r * b_hh[256 + t]);
    float hv = (1.f - z) * nn;
    out_h[(size_t)n * 128 + t] = hv;
    hc[t] = hv;
    if (t == 0) { hc[128] = cI[n]; hc[129] = cR[n]; }
    __syncthreads();
    if (t < 32) {
        const float* Wr;
        float bb;
        int p;
        if (t < 15)      { p = t;      Wr = W_I + p * 130;   bb = b_I[p]; }
        else if (t < 30) { p = t - 15; Wr = W_R + p * 130;   bb = b_R[p]; }
        else             { p = t - 30; Wr = W_sir + p * 130; bb = b_sir[p]; }
        float s = bb;
        for (int d = 0; d < 130; d++) s += hc[d] * Wr[d];
        if (t < 15)      out_predI[(size_t)n * 15 + p] = s;
        else if (t < 30) out_predR[(size_t)n * 15 + p] = s;
        else             s_pr[p] = s;
    }
    __syncthreads();
    if (t == 0) {
        float alpha = 1.f / (1.f + expf(-s_pr[0]));
        float beta  = 1.f / (1.f + expf(-s_pr[1]));
        float Nv = Npop[n];
        float Iv = I0[n], Rv = R0[n];
        float S = Nv - Iv - Rv;
        float SoN = S / Nv;
        for (int st = 0; st < 15; st++) {
            float dIv = alpha * Iv * SoN - beta * Iv;
            float dRv = beta * Iv;
            out_phyI[(size_t)n * 15 + st] = dIv;
            out_phyR[(size_t)n * 15 + st] = dRv;
            Iv += dIv; Rv += dRv;
        }
    }
}

extern "C" void kernel_launch(void* const* d_in, const int* in_sizes, int n_in,
                              void* d_out, int out_size, void* d_ws, size_t ws_size,
                              hipStream_t stream) {
    const float* dynamic = (const float*)d_in[0];
    const int*   ei      = (const int*)d_in[1];
    const float* cI      = (const float*)d_in[2];
    const float* cR      = (const float*)d_in[3];
    const float* Npop    = (const float*)d_in[4];
    const float* I0      = (const float*)d_in[5];
    const float* R0      = (const float*)d_in[6];
    const float* W1      = (const float*)d_in[9];
    const float* a_src1  = (const float*)d_in[10];
    const float* a_dst1  = (const float*)d_in[11];
    const float* b1      = (const float*)d_in[12];
    const float* W2      = (const float*)d_in[13];
    const float* a_src2  = (const float*)d_in[14];
    const float* a_dst2  = (const float*)d_in[15];
    const float* b2      = (const float*)d_in[16];
    const float* W_ih    = (const float*)d_in[17];
    const float* b_ih    = (const float*)d_in[19];
    const float* b_hh    = (const float*)d_in[20];
    const float* W_I     = (const float*)d_in[21];
    const float* b_I     = (const float*)d_in[22];
    const float* W_R     = (const float*)d_in[23];
    const float* b_R     = (const float*)d_in[24];
    const float* W_sir   = (const float*)d_in[25];
    const float* b_sir   = (const float*)d_in[26];
    float* out = (float*)d_out;

    // ---- workspace layout (~60 MB) ----
    int* wsi = (int*)d_ws;
    int* offs    = wsi;              // 20001 (pad 20096)
    int* deg     = wsi + 20096;      // 20000 (pad 20096)
    int* rsum    = wsi + 40192;      // 128
    int* rbase   = wsi + 40320;      // 128
    int* csr_src = wsi + 40448;      // 660000 (pad 660096)
    float* fp = (float*)(wsi + 700544);
    float* w1f = fp; fp += 1152;     // 128*8
    float* w2f = fp; fp += 640;      // 256*2
    float* al1 = fp; fp += 80128;    // 20000*4
    float* ar1 = fp; fp += 80128;
    float* al2 = fp; fp += 20096;
    float* ar2 = fp; fp += 20096;
    ushort* dyn_bf = (ushort*)fp; fp += 1280000;   // 20000*128 bf16
    float* x1 = fp; fp += 5120000;                 // [20000][256] f32; later x2 [20000][128]
    float* R  = fp; fp += 7680000;                 // agg_bf / xl2_bf / gi
    ushort* agg_bf = (ushort*)R;                   // [20000][512] bf16
    ushort* xl2_bf = (ushort*)R;                   // [20000][128] bf16 (after agg dead)
    float* gi = R;                                 // [20000][384] f32 (after xl2 dead)
    float* x2 = x1;                                // [20000][128] f32 (after x1 dead)

    // CSR build: range-partitioned histogram -> tiny scan -> range-partitioned fill
    pre1_kernel<<<NB + 2, 256, 0, stream>>>(ei, deg, rsum, W1, a_src1, a_dst1, w1f,
                                            W2, a_src2, a_dst2, w2f);
    scan_small<<<1, 64, 0, stream>>>(rsum, rbase);
    pre2_kernel<<<NB + 5000, 256, 0, stream>>>(ei, deg, rbase, offs, csr_src,
                                               dynamic, w1f, dyn_bf, al1, ar1);

    // GAT layer 1
    gat_gather_w<4, false><<<2500, 256, 0, stream>>>(dyn_bf, al1, ar1, offs, csr_src, nullptr, agg_bf);
    gemm3t<0, false, 1, false, 64><<<dim3(157, 1, 4), 256, 0, stream>>>(
        agg_bf, W1, b1, x1, NN, 128, 512, 256, 256, 128, 64, 64);

    // GAT layer 2
    alar_apply2<<<5000, 256, 0, stream>>>(x1, w2f, al2, ar2);
    gemm3t<1, false, 0, true, 128><<<dim3(157, 1, 1), 256, 0, stream>>>(
        x1, W2, nullptr, xl2_bf, NN, 256, 256, 128, 128, 0, 0, 0);
    gat_gather_w<1, true><<<2500, 256, 0, stream>>>(xl2_bf, al2, ar2, offs, csr_src, b2, x2);

    // gi = x2 @ W_ih^T
    gemm3t<1, true, 0, false, 128><<<dim3(157, 3, 1), 256, 0, stream>>>(
        x2, W_ih, nullptr, gi, NN, 128, 128, 128, 384, 0, 0, 0);

    // GRU + prediction heads + SIR
    gru_heads_kernel<<<NN, 128, 0, stream>>>(gi, b_ih, b_hh, cI, cR, Npop, I0, R0,
                                             W_I, b_I, W_R, b_R, W_sir, b_sir,
                                             out, out + 300000, out + 600000,
                                             out + 900000, out + 1200000);
}

// Round 6
// 254.947 us; speedup vs baseline: 2.8478x; 2.8478x over previous
//
#include <hip/hip_runtime.h>

#define NN 20000
#define NE 640000
#define NET (NE + NN)   // 660000 edges incl. self-loops
#define NB 128          // dst buckets
#define RR 157          // nodes per bucket (ceil 20000/128)
#define NSL 256         // edge slices
#define ESL4 625        // int4 per slice (2500 edges)

typedef __attribute__((ext_vector_type(8))) short bf16x8;
typedef __attribute__((ext_vector_type(4))) float f32x4;

__device__ inline ushort f2bf_rne(float x) {
    unsigned u = __float_as_uint(x);
    return (ushort)((u + 0x7FFFu + ((u >> 16) & 1u)) >> 16);
}
__device__ inline float bf2f(ushort u) {
    return __uint_as_float(((unsigned)u) << 16);
}
__device__ inline void split2(float x, ushort& hi, ushort& lo) {
    unsigned u = __float_as_uint(x);
    unsigned r = (u + 0x7FFFu + ((u >> 16) & 1u)) & 0xFFFF0000u;  // RNE to bf16
    hi = (ushort)(r >> 16);
    lo = f2bf_rne(x - __uint_as_float(r));   // x - hi is exact
}

// ---------------- csrA: per-slice bucket histogram + weight folds ----------------
__global__ void csrA_kernel(const int* __restrict__ ei, int* __restrict__ cnt,
                            const float* __restrict__ W1, const float* __restrict__ as1,
                            const float* __restrict__ ad1, float* __restrict__ w1f,
                            const float* __restrict__ W2, const float* __restrict__ as2,
                            const float* __restrict__ ad2, float* __restrict__ w2f) {
    int b = blockIdx.x, t = threadIdx.x;
    if (b < NSL) {
        __shared__ int h[NB];
        if (t < NB) h[t] = 0;
        __syncthreads();
        const int4* d4 = (const int4*)(ei + NE);
        for (int i = t; i < ESL4; i += 256) {
            int4 d = d4[b * ESL4 + i];
            atomicAdd(&h[(unsigned)d.x / RR], 1);
            atomicAdd(&h[(unsigned)d.y / RR], 1);
            atomicAdd(&h[(unsigned)d.z / RR], 1);
            atomicAdd(&h[(unsigned)d.w / RR], 1);
        }
        __syncthreads();
        if (t < NB) cnt[t * NSL + b] = h[t];   // bucket-major layout
    } else if (b == NSL) {
        if (t < 128) {
            int k = t;
#pragma unroll
            for (int hh = 0; hh < 4; hh++) {
                float s1 = 0.f, s2 = 0.f;
                for (int c = 0; c < 64; c++) {
                    float w = W1[k * 256 + hh * 64 + c];
                    s1 += w * as1[hh * 64 + c];
                    s2 += w * ad1[hh * 64 + c];
                }
                w1f[k * 8 + hh] = s1;
                w1f[k * 8 + 4 + hh] = s2;
            }
        }
    } else {
        int k = t;  // 256
        float s1 = 0.f, s2 = 0.f;
        for (int c = 0; c < 128; c++) {
            float w = W2[k * 128 + c];
            s1 += w * as2[c];
            s2 += w * ad2[c];
        }
        w2f[k * 2] = s1;
        w2f[k * 2 + 1] = s2;
    }
}

// ---------------- csrB: exclusive scan of 32768 counts (bucket-major) ----------------
__global__ void csrB_kernel(const int* __restrict__ cnt, int* __restrict__ sbase) {
    __shared__ int swsum[16], swsum2[16];
    __shared__ int s_carry;
    int t = threadIdx.x, wv = t >> 6, ln = t & 63;
    if (t == 0) s_carry = 0;
    __syncthreads();
    for (int base = 0; base < NB * NSL; base += 1024) {
        int v = cnt[base + t];
        int s = v;
#pragma unroll
        for (int o = 1; o < 64; o <<= 1) { int u = __shfl_up(s, o, 64); if (ln >= o) s += u; }
        if (ln == 63) swsum[wv] = s;
        __syncthreads();
        if (t < 16) {
            int sv = swsum[t];
#pragma unroll
            for (int o = 1; o < 16; o <<= 1) { int u = __shfl_up(sv, o, 16); if (t >= o) sv += u; }
            swsum2[t] = sv;
        }
        __syncthreads();
        sbase[base + t] = s_carry + (wv ? swsum2[wv - 1] : 0) + s - v;
        __syncthreads();
        if (t == 0) s_carry += swsum2[15];
        __syncthreads();
    }
}

// ---------------- csrC: slice scatter into ebuf + alar_cast ----------------
__global__ void csrC_kernel(const int* __restrict__ ei, const int* __restrict__ sbase,
                            int2* __restrict__ ebuf, const float* __restrict__ X,
                            const float* __restrict__ wf, ushort* __restrict__ Xbf,
                            float* __restrict__ al, float* __restrict__ ar) {
    int b = blockIdx.x, t = threadIdx.x;
    if (b < NSL) {
        __shared__ int cur[NB];
        if (t < NB) cur[t] = sbase[t * NSL + b];
        __syncthreads();
        const int4* s4 = (const int4*)ei;
        const int4* d4 = (const int4*)(ei + NE);
        for (int i = t; i < ESL4; i += 256) {
            int4 sv = s4[b * ESL4 + i];
            int4 dv = d4[b * ESL4 + i];
            int p;
            p = atomicAdd(&cur[(unsigned)dv.x / RR], 1); ebuf[p] = make_int2(sv.x, dv.x);
            p = atomicAdd(&cur[(unsigned)dv.y / RR], 1); ebuf[p] = make_int2(sv.y, dv.y);
            p = atomicAdd(&cur[(unsigned)dv.z / RR], 1); ebuf[p] = make_int2(sv.z, dv.z);
            p = atomicAdd(&cur[(unsigned)dv.w / RR], 1); ebuf[p] = make_int2(sv.w, dv.w);
        }
    } else {
        __shared__ float ws[8][128];
        for (int i = t; i < 1024; i += 256) ws[i & 7][i >> 3] = wf[i];
        __syncthreads();
        int wv = t >> 6, ln = t & 63;
        int n = (b - NSL) * 4 + wv;
        float2 xv = *(const float2*)(X + (size_t)n * 128 + ln * 2);
        ushort2 ub;
        ub.x = f2bf_rne(xv.x);
        ub.y = f2bf_rne(xv.y);
        *(ushort2*)(Xbf + (size_t)n * 128 + ln * 2) = ub;
        float p[8];
#pragma unroll
        for (int o = 0; o < 8; o++) p[o] = xv.x * ws[o][ln * 2] + xv.y * ws[o][ln * 2 + 1];
#pragma unroll
        for (int off = 32; off > 0; off >>= 1)
#pragma unroll
            for (int o = 0; o < 8; o++) p[o] += __shfl_xor(p[o], off, 64);
        if (ln == 0) {
#pragma unroll
            for (int h = 0; h < 4; h++) {
                al[n * 4 + h] = p[h];
                ar[n * 4 + h] = p[4 + h];
            }
        }
    }
}

// ---------------- csrD: per-bucket local CSR build ----------------
__global__ void csrD_kernel(const int2* __restrict__ ebuf, const int* __restrict__ sbase,
                            int* __restrict__ offs, int* __restrict__ csr_src) {
    __shared__ int hist[RR], lcur[RR];
    int b = blockIdx.x, t = threadIdx.x;
    int lo = b * RR;
    int Ra = min(RR, NN - lo);
    int e0 = sbase[b * NSL];
    int e1 = (b < NB - 1) ? sbase[(b + 1) * NSL] : NE;
    int m = e1 - e0;
    for (int i = t; i < Ra; i += 256) hist[i] = 0;
    __syncthreads();
    for (int j = t; j < m; j += 256) atomicAdd(&hist[ebuf[e0 + j].y - lo], 1);
    __syncthreads();
    if (t < 64) {
        int cbase = e0 + lo;   // earlier buckets contribute e0 edges + lo self-loops
        int carry = 0;
#pragma unroll
        for (int c = 0; c < 3; c++) {
            int i = c * 64 + t;
            int v = (i < Ra) ? hist[i] + 1 : 0;   // +1 self-loop
            int s = v;
#pragma unroll
            for (int o = 1; o < 64; o <<= 1) { int u = __shfl_up(s, o, 64); if (t >= o) s += u; }
            if (i < Ra) {
                int off = cbase + carry + s - v;
                offs[lo + i] = off;
                lcur[i] = off;
            }
            carry += __shfl(s, 63, 64);
        }
    }
    if (b == 0 && t == 255) offs[NN] = NET;
    __syncthreads();
    // self-loop in last slot of each segment
    for (int i = t; i < Ra; i += 256) csr_src[lcur[i] + hist[i]] = lo + i;
    __syncthreads();
    for (int j = t; j < m; j += 256) {
        int2 p = ebuf[e0 + j];
        int pos = atomicAdd(&lcur[p.y - lo], 1);
        csr_src[pos] = p.x;
    }
}

// ---------------- layer-2 al/ar = x1 @ w2f ----------------
__launch_bounds__(256)
__global__ void alar_apply2(const float* __restrict__ X, const float* __restrict__ wf,
                            float* __restrict__ al, float* __restrict__ ar) {
    __shared__ float ws[2][256];
    int t = threadIdx.x;
    for (int i = t; i < 512; i += 256) ws[i & 1][i >> 1] = wf[i];
    __syncthreads();
    int wv = t >> 6, ln = t & 63;
    int n = blockIdx.x * 4 + wv;
    float p0 = 0.f, p1 = 0.f;
#pragma unroll
    for (int cc = 0; cc < 4; cc++) {
        int c = ln * 4 + cc;
        float x = X[(size_t)n * 256 + c];
        p0 += x * ws[0][c];
        p1 += x * ws[1][c];
    }
#pragma unroll
    for (int off = 32; off > 0; off >>= 1) {
        p0 += __shfl_xor(p0, off, 64);
        p1 += __shfl_xor(p1, off, 64);
    }
    if (ln == 0) { al[n] = p0; ar[n] = p1; }
}

// ---------------- GAT gather: half-wave per node, register-only softmax ----------------
template <int H, bool FUSE>
__launch_bounds__(256)
__global__ void gat_gather_w(const ushort* __restrict__ X, const float* __restrict__ al,
                             const float* __restrict__ ar, const int* __restrict__ offs,
                             const int* __restrict__ csr, const float* __restrict__ bias,
                             void* __restrict__ outp) {
    int t = threadIdx.x;
    int wv = t >> 6, ln = t & 63;
    int hw = ln >> 5, l32 = ln & 31;
    int n = blockIdx.x * 8 + wv * 2 + hw;
    int e0 = offs[n], e1 = offs[n + 1];

    float arv[H], m[H], srun[H], acc[4][H];
#pragma unroll
    for (int h = 0; h < H; h++) {
        arv[h] = ar[n * H + h];
        m[h] = -1e30f; srun[h] = 0.f;
#pragma unroll
        for (int c = 0; c < 4; c++) acc[c][h] = 0.f;
    }
    const ushort* Xc = X + (size_t)l32 * 4;

    for (int base = e0; base < e1; base += 64) {
        int cnt = e1 - base; if (cnt > 64) cnt = 64;
        bool vA = l32 < cnt, vB = l32 + 32 < cnt;
        int srcA = 0, srcB = 0;
        float wA[H], wB[H], lmx[H];
#pragma unroll
        for (int h = 0; h < H; h++) { lmx[h] = -1e30f; wA[h] = 0.f; wB[h] = 0.f; }
        if (vA) {
            srcA = csr[base + l32];
            float av[H];
            if (H == 4) {
                float4 a4 = *(const float4*)(al + (size_t)srcA * 4);
                av[0] = a4.x; av[H > 1 ? 1 : 0] = a4.y;
                av[H > 2 ? 2 : 0] = a4.z; av[H > 3 ? 3 : 0] = a4.w;
            } else {
                av[0] = al[srcA];
            }
#pragma unroll
            for (int h = 0; h < H; h++) {
                float lg = av[h] + arv[h];
                lg = lg > 0.f ? lg : 0.2f * lg;
                wA[h] = lg;
                lmx[h] = fmaxf(lmx[h], lg);
            }
        }
        if (vB) {
            srcB = csr[base + l32 + 32];
            float av[H];
            if (H == 4) {
                float4 a4 = *(const float4*)(al + (size_t)srcB * 4);
                av[0] = a4.x; av[H > 1 ? 1 : 0] = a4.y;
                av[H > 2 ? 2 : 0] = a4.z; av[H > 3 ? 3 : 0] = a4.w;
            } else {
                av[0] = al[srcB];
            }
#pragma unroll
            for (int h = 0; h < H; h++) {
                float lg = av[h] + arv[h];
                lg = lg > 0.f ? lg : 0.2f * lg;
                wB[h] = lg;
                lmx[h] = fmaxf(lmx[h], lg);
            }
        }
#pragma unroll
        for (int off = 16; off > 0; off >>= 1)
#pragma unroll
            for (int h = 0; h < H; h++) lmx[h] = fmaxf(lmx[h], __shfl_xor(lmx[h], off, 32));
        float ls[H];
#pragma unroll
        for (int h = 0; h < H; h++) {
            float mn = fmaxf(m[h], lmx[h]);
            float sc = __expf(m[h] - mn);
            m[h] = mn;
            srun[h] *= sc;
#pragma unroll
            for (int c = 0; c < 4; c++) acc[c][h] *= sc;
            float a = vA ? __expf(wA[h] - mn) : 0.f;
            float b = vB ? __expf(wB[h] - mn) : 0.f;
            wA[h] = a; wB[h] = b;
            ls[h] = a + b;
        }
#pragma unroll
        for (int off = 16; off > 0; off >>= 1)
#pragma unroll
            for (int h = 0; h < H; h++) ls[h] += __shfl_xor(ls[h], off, 32);
#pragma unroll
        for (int h = 0; h < H; h++) srun[h] += ls[h];

        int k = 0;
        for (; k + 4 <= cnt; k += 4) {
            int r4[4]; float w4[4][H];
            if (k < 32) {
#pragma unroll
                for (int q = 0; q < 4; q++) {
                    r4[q] = __shfl(srcA, k + q, 32);
#pragma unroll
                    for (int h = 0; h < H; h++) w4[q][h] = __shfl(wA[h], k + q, 32);
                }
            } else {
#pragma unroll
                for (int q = 0; q < 4; q++) {
                    r4[q] = __shfl(srcB, k - 32 + q, 32);
#pragma unroll
                    for (int h = 0; h < H; h++) w4[q][h] = __shfl(wB[h], k - 32 + q, 32);
                }
            }
            uint2 u[4];
#pragma unroll
            for (int q = 0; q < 4; q++) u[q] = *(const uint2*)(Xc + (size_t)r4[q] * 128);
#pragma unroll
            for (int q = 0; q < 4; q++) {
                float x0 = __uint_as_float(u[q].x << 16);
                float x1 = __uint_as_float(u[q].x & 0xffff0000u);
                float x2 = __uint_as_float(u[q].y << 16);
                float x3 = __uint_as_float(u[q].y & 0xffff0000u);
#pragma unroll
                for (int h = 0; h < H; h++) {
                    acc[0][h] = fmaf(w4[q][h], x0, acc[0][h]);
                    acc[1][h] = fmaf(w4[q][h], x1, acc[1][h]);
                    acc[2][h] = fmaf(w4[q][h], x2, acc[2][h]);
                    acc[3][h] = fmaf(w4[q][h], x3, acc[3][h]);
                }
            }
        }
        for (; k < cnt; k++) {
            int r; float wk[H];
            if (k < 32) {
                r = __shfl(srcA, k, 32);
#pragma unroll
                for (int h = 0; h < H; h++) wk[h] = __shfl(wA[h], k, 32);
            } else {
                r = __shfl(srcB, k - 32, 32);
#pragma unroll
                for (int h = 0; h < H; h++) wk[h] = __shfl(wB[h], k - 32, 32);
            }
            uint2 u = *(const uint2*)(Xc + (size_t)r * 128);
            float x0 = __uint_as_float(u.x << 16);
            float x1 = __uint_as_float(u.x & 0xffff0000u);
            float x2 = __uint_as_float(u.y << 16);
            float x3 = __uint_as_float(u.y & 0xffff0000u);
#pragma unroll
            for (int h = 0; h < H; h++) {
                acc[0][h] = fmaf(wk[h], x0, acc[0][h]);
                acc[1][h] = fmaf(wk[h], x1, acc[1][h]);
                acc[2][h] = fmaf(wk[h], x2, acc[2][h]);
                acc[3][h] = fmaf(wk[h], x3, acc[3][h]);
            }
        }
    }
    if (FUSE) {
        float* out = (float*)outp;
        float inv = 1.f / srun[0];
        const float* bp = bias + l32 * 4;
        float4 o;
        float v0 = acc[0][0] * inv + bp[0];
        float v1 = acc[1][0] * inv + bp[1];
        float v2 = acc[2][0] * inv + bp[2];
        float v3 = acc[3][0] * inv + bp[3];
        o.x = v0 > 0.f ? v0 : __expf(v0) - 1.f;
        o.y = v1 > 0.f ? v1 : __expf(v1) - 1.f;
        o.z = v2 > 0.f ? v2 : __expf(v2) - 1.f;
        o.w = v3 > 0.f ? v3 : __expf(v3) - 1.f;
        *(float4*)(out + (size_t)n * 128 + l32 * 4) = o;
    } else {
        ushort* out = (ushort*)outp;
#pragma unroll
        for (int h = 0; h < H; h++) {
            float inv = 1.f / srun[h];
            ushort4 o = make_ushort4(f2bf_rne(acc[0][h] * inv), f2bf_rne(acc[1][h] * inv),
                                     f2bf_rne(acc[2][h] * inv), f2bf_rne(acc[3][h] * inv));
            *(ushort4*)(out + (size_t)n * (H * 128) + h * 128 + l32 * 4) = o;
        }
    }
}

// ---------------- MFMA split-bf16 GEMM ----------------
template <int ASPLIT, bool BT, int ACT, bool OUTBF, int BN>
__launch_bounds__(256)
__global__ void gemm3t(const void* __restrict__ Aptr, const float* __restrict__ B,
                       const float* __restrict__ bias, void* __restrict__ Cptr,
                       int M, int K, int lda, int ldb, int ldc, int zA, int zB, int zC) {
    constexpr int NF = BN / 32;
    __shared__ ushort Ah[128 * 64];
    __shared__ ushort Al[ASPLIT ? 128 * 64 : 64];
    __shared__ ushort Bh[64 * BN];
    __shared__ ushort Bl[64 * BN];
    int tid = threadIdx.x;
    int z = blockIdx.z;
    int bm = blockIdx.x * 128;
    int ny = blockIdx.y * BN;
    int wid = tid >> 6, ln = tid & 63;
    int wm = wid >> 1, wn = wid & 1;
    f32x4 acc[4][NF];
#pragma unroll
    for (int a = 0; a < 4; a++)
#pragma unroll
        for (int b = 0; b < NF; b++)
#pragma unroll
            for (int j = 0; j < 4; j++) acc[a][b][j] = 0.f;
    const float* Af = (const float*)Aptr;
    const ushort* Au = (const ushort*)Aptr;
    size_t abase = (size_t)z * zA;
    int bcb = z * zB + ny;

    for (int k0 = 0; k0 < K; k0 += 64) {
#pragma unroll
        for (int i = 0; i < 8; i++) {
            int idx = tid + i * 256;
            int r = idx >> 4, c4 = (idx & 15) * 4;
            int gr = bm + r;
            int ab = (r * 128 + c4 * 2) ^ ((r & 7) << 4);
            if (ASPLIT) {
                float4 v = make_float4(0.f, 0.f, 0.f, 0.f);
                if (gr < M) v = *(const float4*)(Af + abase + (size_t)gr * lda + k0 + c4);
                ushort h0, h1, h2, h3, l0, l1, l2, l3;
                split2(v.x, h0, l0); split2(v.y, h1, l1);
                split2(v.z, h2, l2); split2(v.w, h3, l3);
                *(ushort4*)((char*)Ah + ab) = make_ushort4(h0, h1, h2, h3);
                *(ushort4*)((char*)Al + ab) = make_ushort4(l0, l1, l2, l3);
            } else {
                ushort4 v = make_ushort4(0, 0, 0, 0);
                if (gr < M) v = *(const ushort4*)(Au + abase + (size_t)gr * lda + k0 + c4);
                *(ushort4*)((char*)Ah + ab) = v;
            }
        }
        if (!BT) {
#pragma unroll
            for (int i = 0; i < BN / 16; i++) {
                int idx = tid + i * 256;
                int kk = idx / (BN / 4);
                int c4 = (idx % (BN / 4)) * 4;
                float4 v = *(const float4*)(B + (size_t)(k0 + kk) * ldb + bcb + c4);
                float vv[4] = {v.x, v.y, v.z, v.w};
#pragma unroll
                for (int q = 0; q < 4; q++) {
                    int nl = c4 + q;
                    int bb = (nl * 128 + kk * 2) ^ ((nl & 7) << 4);
                    ushort h, l;
                    split2(vv[q], h, l);
                    *(ushort*)((char*)Bh + bb) = h;
                    *(ushort*)((char*)Bl + bb) = l;
                }
            }
        } else {
#pragma unroll
            for (int i = 0; i < BN / 16; i++) {
                int idx = tid + i * 256;
                int nl = idx >> 4, k4 = (idx & 15) * 4;
                float4 v = *(const float4*)(B + (size_t)(ny + nl) * ldb + k0 + k4);
                ushort h0, h1, h2, h3, l0, l1, l2, l3;
                split2(v.x, h0, l0); split2(v.y, h1, l1);
                split2(v.z, h2, l2); split2(v.w, h3, l3);
                int bb = (nl * 128 + k4 * 2) ^ ((nl & 7) << 4);
                *(ushort4*)((char*)Bh + bb) = make_ushort4(h0, h1, h2, h3);
                *(ushort4*)((char*)Bl + bb) = make_ushort4(l0, l1, l2, l3);
            }
        }
        __syncthreads();
#pragma unroll
        for (int ks = 0; ks < 2; ks++) {
            int kb = ks * 64 + (ln >> 4) * 16;
            bf16x8 ah[4], alo[ASPLIT ? 4 : 1], bh[NF], bl[NF];
#pragma unroll
            for (int mf = 0; mf < 4; mf++) {
                int r = wm * 64 + mf * 16 + (ln & 15);
                int ab = (r * 128 + kb) ^ ((r & 7) << 4);
                ah[mf] = *(bf16x8*)((char*)Ah + ab);
                if (ASPLIT) alo[mf] = *(bf16x8*)((char*)Al + ab);
            }
#pragma unroll
            for (int nf = 0; nf < NF; nf++) {
                int nl = wn * (BN / 2) + nf * 16 + (ln & 15);
                int bb = (nl * 128 + kb) ^ ((nl & 7) << 4);
                bh[nf] = *(bf16x8*)((char*)Bh + bb);
                bl[nf] = *(bf16x8*)((char*)Bl + bb);
            }
#pragma unroll
            for (int mf = 0; mf < 4; mf++)
#pragma unroll
                for (int nf = 0; nf < NF; nf++) {
                    acc[mf][nf] = __builtin_amdgcn_mfma_f32_16x16x32_bf16(ah[mf], bh[nf], acc[mf][nf], 0, 0, 0);
                    acc[mf][nf] = __builtin_amdgcn_mfma_f32_16x16x32_bf16(ah[mf], bl[nf], acc[mf][nf], 0, 0, 0);
                    if (ASPLIT)
                        acc[mf][nf] = __builtin_amdgcn_mfma_f32_16x16x32_bf16(alo[mf], bh[nf], acc[mf][nf], 0, 0, 0);
                }
        }
        __syncthreads();
    }
    float* Cf = (float*)Cptr;
    ushort* Cu = (ushort*)Cptr;
#pragma unroll
    for (int mf = 0; mf < 4; mf++)
#pragma unroll
        for (int nf = 0; nf < NF; nf++) {
            int colL = ny + wn * (BN / 2) + nf * 16 + (ln & 15);
#pragma unroll
            for (int j = 0; j < 4; j++) {
                int row = bm + wm * 64 + mf * 16 + (ln >> 4) * 4 + j;
                if (row < M) {
                    float v = acc[mf][nf][j];
                    if (ACT) {
                        v += bias[z * zC + colL];
                        v = v > 0.f ? v : (__expf(v) - 1.f);
                    }
                    size_t ci = (size_t)row * ldc + z * zC + colL;
                    if (OUTBF) Cu[ci] = f2bf_rne(v);
                    else       Cf[ci] = v;
                }
            }
        }
}

// ---------------- GRU (h0=0) + heads + SIR physics ----------------
__launch_bounds__(128)
__global__ void gru_heads_kernel(const float* __restrict__ gi, const float* __restrict__ b_ih,
                                 const float* __restrict__ b_hh, const float* __restrict__ cI,
                                 const float* __restrict__ cR, const float* __restrict__ Npop,
                                 const float* __restrict__ I0, const float* __restrict__ R0,
                                 const float* __restrict__ W_I, const float* __restrict__ b_I,
                                 const float* __restrict__ W_R, const float* __restrict__ b_R,
                                 const float* __restrict__ W_sir, const float* __restrict__ b_sir,
                                 float* __restrict__ out_predI, float* __restrict__ out_predR,
                                 float* __restrict__ out_phyI, float* __restrict__ out_phyR,
                                 float* __restrict__ out_h) {
    int n = blockIdx.x, t = threadIdx.x;
    __shared__ float hc[130];
    __shared__ float s_pr[2];
    const float* g = gi + (size_t)n * 384;
    float ir = g[t] + b_ih[t];
    float iz = g[128 + t] + b_ih[128 + t];
    float ih = g[256 + t] + b_ih[256 + t];
    float r = 1.f / (1.f + expf(-(ir + b_hh[t])));
    float z = 1.f / (1.f + expf(-(iz + b_hh[128 + t])));
    float nn = tanhf(ih + r * b_hh[256 + t]);
    float hv = (1.f - z) * nn;
    out_h[(size_t)n * 128 + t] = hv;
    hc[t] = hv;
    if (t == 0) { hc[128] = cI[n]; hc[129] = cR[n]; }
    __syncthreads();
    if (t < 32) {
        const float* Wr;
        float bb;
        int p;
        if (t < 15)      { p = t;      Wr = W_I + p * 130;   bb = b_I[p]; }
        else if (t < 30) { p = t - 15; Wr = W_R + p * 130;   bb = b_R[p]; }
        else             { p = t - 30; Wr = W_sir + p * 130; bb = b_sir[p]; }
        float s = bb;
        for (int d = 0; d < 130; d++) s += hc[d] * Wr[d];
        if (t < 15)      out_predI[(size_t)n * 15 + p] = s;
        else if (t < 30) out_predR[(size_t)n * 15 + p] = s;
        else             s_pr[p] = s;
    }
    __syncthreads();
    if (t == 0) {
        float alpha = 1.f / (1.f + expf(-s_pr[0]));
        float beta  = 1.f / (1.f + expf(-s_pr[1]));
        float Nv = Npop[n];
        float Iv = I0[n], Rv = R0[n];
        float S = Nv - Iv - Rv;
        float SoN = S / Nv;
        for (int st = 0; st < 15; st++) {
            float dIv = alpha * Iv * SoN - beta * Iv;
            float dRv = beta * Iv;
            out_phyI[(size_t)n * 15 + st] = dIv;
            out_phyR[(size_t)n * 15 + st] = dRv;
            Iv += dIv; Rv += dRv;
        }
    }
}

extern "C" void kernel_launch(void* const* d_in, const int* in_sizes, int n_in,
                              void* d_out, int out_size, void* d_ws, size_t ws_size,
                              hipStream_t stream) {
    const float* dynamic = (const float*)d_in[0];
    const int*   ei      = (const int*)d_in[1];
    const float* cI      = (const float*)d_in[2];
    const float* cR      = (const float*)d_in[3];
    const float* Npop    = (const float*)d_in[4];
    const float* I0      = (const float*)d_in[5];
    const float* R0      = (const float*)d_in[6];
    const float* W1      = (const float*)d_in[9];
    const float* a_src1  = (const float*)d_in[10];
    const float* a_dst1  = (const float*)d_in[11];
    const float* b1      = (const float*)d_in[12];
    const float* W2      = (const float*)d_in[13];
    const float* a_src2  = (const float*)d_in[14];
    const float* a_dst2  = (const float*)d_in[15];
    const float* b2      = (const float*)d_in[16];
    const float* W_ih    = (const float*)d_in[17];
    const float* b_ih    = (const float*)d_in[19];
    const float* b_hh    = (const float*)d_in[20];
    const float* W_I     = (const float*)d_in[21];
    const float* b_I     = (const float*)d_in[22];
    const float* W_R     = (const float*)d_in[23];
    const float* b_R     = (const float*)d_in[24];
    const float* W_sir   = (const float*)d_in[25];
    const float* b_sir   = (const float*)d_in[26];
    float* out = (float*)d_out;

    // ---- workspace layout (~60 MB) ----
    int* wsi = (int*)d_ws;
    int* offs    = wsi;              // 20001 (pad 20096)
    int* csr_src = wsi + 20096;      // 660000 (pad 660096)
    int* cnt     = wsi + 680192;     // 32768
    int* sbase   = wsi + 712960;     // 32768
    float* fp = (float*)(wsi + 745728);
    float* w1f = fp; fp += 1152;     // 128*8
    float* w2f = fp; fp += 640;      // 256*2
    float* al1 = fp; fp += 80128;    // 20000*4
    float* ar1 = fp; fp += 80128;
    float* al2 = fp; fp += 20096;
    float* ar2 = fp; fp += 20096;
    ushort* dyn_bf = (ushort*)fp; fp += 1280000;   // 20000*128 bf16
    float* x1 = fp; fp += 5120000;                 // [20000][256] f32; later x2 [20000][128]
    float* R  = fp; fp += 7680000;                 // ebuf / agg_bf / xl2_bf / gi
    int2* ebuf = (int2*)R;                         // [640000] int2 (dead before agg_bf live)
    ushort* agg_bf = (ushort*)R;                   // [20000][512] bf16
    ushort* xl2_bf = (ushort*)R;                   // [20000][128] bf16 (after agg dead)
    float* gi = R;                                 // [20000][384] f32 (after xl2 dead)
    float* x2 = x1;                                // [20000][128] f32 (after x1 dead)

    // CSR build: slice histogram -> scan -> slice scatter -> bucket-local CSR
    csrA_kernel<<<NSL + 2, 256, 0, stream>>>(ei, cnt, W1, a_src1, a_dst1, w1f,
                                             W2, a_src2, a_dst2, w2f);
    csrB_kernel<<<1, 1024, 0, stream>>>(cnt, sbase);
    csrC_kernel<<<NSL + 5000, 256, 0, stream>>>(ei, sbase, ebuf, dynamic, w1f,
                                                dyn_bf, al1, ar1);
    csrD_kernel<<<NB, 256, 0, stream>>>(ebuf, sbase, offs, csr_src);

    // GAT layer 1
    gat_gather_w<4, false><<<2500, 256, 0, stream>>>(dyn_bf, al1, ar1, offs, csr_src, nullptr, agg_bf);
    gemm3t<0, false, 1, false, 64><<<dim3(157, 1, 4), 256, 0, stream>>>(
        agg_bf, W1, b1, x1, NN, 128, 512, 256, 256, 128, 64, 64);

    // GAT layer 2
    alar_apply2<<<5000, 256, 0, stream>>>(x1, w2f, al2, ar2);
    gemm3t<1, false, 0, true, 128><<<dim3(157, 1, 1), 256, 0, stream>>>(
        x1, W2, nullptr, xl2_bf, NN, 256, 256, 128, 128, 0, 0, 0);
    gat_gather_w<1, true><<<2500, 256, 0, stream>>>(xl2_bf, al2, ar2, offs, csr_src, b2, x2);

    // gi = x2 @ W_ih^T
    gemm3t<1, true, 0, false, 128><<<dim3(157, 3, 1), 256, 0, stream>>>(
        x2, W_ih, nullptr, gi, NN, 128, 128, 128, 384, 0, 0, 0);

    // GRU + prediction heads + SIR
    gru_heads_kernel<<<NN, 128, 0, stream>>>(gi, b_ih, b_hh, cI, cR, Npop, I0, R0,
                                             W_I, b_I, W_R, b_R, W_sir, b_sir,
                                             out, out + 300000, out + 600000,
                                             out + 900000, out + 1200000);
}

// Round 7
// 253.774 us; speedup vs baseline: 2.8610x; 1.0046x over previous
//
#include <hip/hip_runtime.h>

#define NN 20000
#define NE 640000
#define NET (NE + NN)   // 660000 edges incl. self-loops
#define NB 128          // dst buckets
#define RR 157          // nodes per bucket (ceil 20000/128)
#define NSL 256         // edge slices
#define ESL4 625        // int4 per slice (2500 edges)

typedef __attribute__((ext_vector_type(8))) short bf16x8;
typedef __attribute__((ext_vector_type(4))) float f32x4;

__device__ inline ushort f2bf_rne(float x) {
    unsigned u = __float_as_uint(x);
    return (ushort)((u + 0x7FFFu + ((u >> 16) & 1u)) >> 16);
}
__device__ inline float bf2f(ushort u) {
    return __uint_as_float(((unsigned)u) << 16);
}
__device__ inline void split2(float x, ushort& hi, ushort& lo) {
    unsigned u = __float_as_uint(x);
    unsigned r = (u + 0x7FFFu + ((u >> 16) & 1u)) & 0xFFFF0000u;  // RNE to bf16
    hi = (ushort)(r >> 16);
    lo = f2bf_rne(x - __uint_as_float(r));   // x - hi is exact
}
__device__ inline float rlane(float x, int k) {
    return __int_as_float(__builtin_amdgcn_readlane(__float_as_int(x), k));
}

// ---------------- csrA: per-slice bucket histogram + weight folds ----------------
__global__ void csrA_kernel(const int* __restrict__ ei, int* __restrict__ cnt,
                            const float* __restrict__ W1, const float* __restrict__ as1,
                            const float* __restrict__ ad1, float* __restrict__ w1f,
                            const float* __restrict__ W2, const float* __restrict__ as2,
                            const float* __restrict__ ad2, float* __restrict__ w2f) {
    int b = blockIdx.x, t = threadIdx.x;
    if (b < NSL) {
        __shared__ int h[NB];
        if (t < NB) h[t] = 0;
        __syncthreads();
        const int4* d4 = (const int4*)(ei + NE);
        for (int i = t; i < ESL4; i += 256) {
            int4 d = d4[b * ESL4 + i];
            atomicAdd(&h[(unsigned)d.x / RR], 1);
            atomicAdd(&h[(unsigned)d.y / RR], 1);
            atomicAdd(&h[(unsigned)d.z / RR], 1);
            atomicAdd(&h[(unsigned)d.w / RR], 1);
        }
        __syncthreads();
        if (t < NB) cnt[t * NSL + b] = h[t];   // bucket-major layout
    } else if (b == NSL) {
        if (t < 128) {
            int k = t;
#pragma unroll
            for (int hh = 0; hh < 4; hh++) {
                float s1 = 0.f, s2 = 0.f;
                for (int c = 0; c < 64; c++) {
                    float w = W1[k * 256 + hh * 64 + c];
                    s1 += w * as1[hh * 64 + c];
                    s2 += w * ad1[hh * 64 + c];
                }
                w1f[k * 8 + hh] = s1;
                w1f[k * 8 + 4 + hh] = s2;
            }
        }
    } else {
        int k = t;  // 256
        float s1 = 0.f, s2 = 0.f;
        for (int c = 0; c < 128; c++) {
            float w = W2[k * 128 + c];
            s1 += w * as2[c];
            s2 += w * ad2[c];
        }
        w2f[k * 2] = s1;
        w2f[k * 2 + 1] = s2;
    }
}

// ---------------- csrB: exclusive scan of 32768 counts (bucket-major) ----------------
__global__ void csrB_kernel(const int* __restrict__ cnt, int* __restrict__ sbase) {
    __shared__ int swsum[16], swsum2[16];
    __shared__ int s_carry;
    int t = threadIdx.x, wv = t >> 6, ln = t & 63;
    if (t == 0) s_carry = 0;
    __syncthreads();
    for (int base = 0; base < NB * NSL; base += 1024) {
        int v = cnt[base + t];
        int s = v;
#pragma unroll
        for (int o = 1; o < 64; o <<= 1) { int u = __shfl_up(s, o, 64); if (ln >= o) s += u; }
        if (ln == 63) swsum[wv] = s;
        __syncthreads();
        if (t < 16) {
            int sv = swsum[t];
#pragma unroll
            for (int o = 1; o < 16; o <<= 1) { int u = __shfl_up(sv, o, 16); if (t >= o) sv += u; }
            swsum2[t] = sv;
        }
        __syncthreads();
        sbase[base + t] = s_carry + (wv ? swsum2[wv - 1] : 0) + s - v;
        __syncthreads();
        if (t == 0) s_carry += swsum2[15];
        __syncthreads();
    }
}

// ---------------- csrC: slice scatter into ebuf + alar_cast ----------------
__global__ void csrC_kernel(const int* __restrict__ ei, const int* __restrict__ sbase,
                            int2* __restrict__ ebuf, const float* __restrict__ X,
                            const float* __restrict__ wf, ushort* __restrict__ Xbf,
                            float* __restrict__ al, float* __restrict__ ar) {
    int b = blockIdx.x, t = threadIdx.x;
    if (b < NSL) {
        __shared__ int cur[NB];
        if (t < NB) cur[t] = sbase[t * NSL + b];
        __syncthreads();
        const int4* s4 = (const int4*)ei;
        const int4* d4 = (const int4*)(ei + NE);
        for (int i = t; i < ESL4; i += 256) {
            int4 sv = s4[b * ESL4 + i];
            int4 dv = d4[b * ESL4 + i];
            int p;
            p = atomicAdd(&cur[(unsigned)dv.x / RR], 1); ebuf[p] = make_int2(sv.x, dv.x);
            p = atomicAdd(&cur[(unsigned)dv.y / RR], 1); ebuf[p] = make_int2(sv.y, dv.y);
            p = atomicAdd(&cur[(unsigned)dv.z / RR], 1); ebuf[p] = make_int2(sv.z, dv.z);
            p = atomicAdd(&cur[(unsigned)dv.w / RR], 1); ebuf[p] = make_int2(sv.w, dv.w);
        }
    } else {
        __shared__ float ws[8][128];
        for (int i = t; i < 1024; i += 256) ws[i & 7][i >> 3] = wf[i];
        __syncthreads();
        int wv = t >> 6, ln = t & 63;
        int n = (b - NSL) * 4 + wv;
        float2 xv = *(const float2*)(X + (size_t)n * 128 + ln * 2);
        ushort2 ub;
        ub.x = f2bf_rne(xv.x);
        ub.y = f2bf_rne(xv.y);
        *(ushort2*)(Xbf + (size_t)n * 128 + ln * 2) = ub;
        float p[8];
#pragma unroll
        for (int o = 0; o < 8; o++) p[o] = xv.x * ws[o][ln * 2] + xv.y * ws[o][ln * 2 + 1];
#pragma unroll
        for (int off = 32; off > 0; off >>= 1)
#pragma unroll
            for (int o = 0; o < 8; o++) p[o] += __shfl_xor(p[o], off, 64);
        if (ln == 0) {
#pragma unroll
            for (int h = 0; h < 4; h++) {
                al[n * 4 + h] = p[h];
                ar[n * 4 + h] = p[4 + h];
            }
        }
    }
}

// ---------------- csrD: per-bucket local CSR build ----------------
__global__ void csrD_kernel(const int2* __restrict__ ebuf, const int* __restrict__ sbase,
                            int* __restrict__ offs, int* __restrict__ csr_src) {
    __shared__ int hist[RR], lcur[RR];
    int b = blockIdx.x, t = threadIdx.x;
    int lo = b * RR;
    int Ra = min(RR, NN - lo);
    int e0 = sbase[b * NSL];
    int e1 = (b < NB - 1) ? sbase[(b + 1) * NSL] : NE;
    int m = e1 - e0;
    for (int i = t; i < Ra; i += 256) hist[i] = 0;
    __syncthreads();
    for (int j = t; j < m; j += 256) atomicAdd(&hist[ebuf[e0 + j].y - lo], 1);
    __syncthreads();
    if (t < 64) {
        int cbase = e0 + lo;   // earlier buckets contribute e0 edges + lo self-loops
        int carry = 0;
#pragma unroll
        for (int c = 0; c < 3; c++) {
            int i = c * 64 + t;
            int v = (i < Ra) ? hist[i] + 1 : 0;   // +1 self-loop
            int s = v;
#pragma unroll
            for (int o = 1; o < 64; o <<= 1) { int u = __shfl_up(s, o, 64); if (t >= o) s += u; }
            if (i < Ra) {
                int off = cbase + carry + s - v;
                offs[lo + i] = off;
                lcur[i] = off;
            }
            carry += __shfl(s, 63, 64);
        }
    }
    if (b == 0 && t == 255) offs[NN] = NET;
    __syncthreads();
    // self-loop in last slot of each segment
    for (int i = t; i < Ra; i += 256) csr_src[lcur[i] + hist[i]] = lo + i;
    __syncthreads();
    for (int j = t; j < m; j += 256) {
        int2 p = ebuf[e0 + j];
        int pos = atomicAdd(&lcur[p.y - lo], 1);
        csr_src[pos] = p.x;
    }
}

// ---------------- layer-2 al/ar = x1 @ w2f ----------------
__launch_bounds__(256)
__global__ void alar_apply2(const float* __restrict__ X, const float* __restrict__ wf,
                            float* __restrict__ al, float* __restrict__ ar) {
    __shared__ float ws[2][256];
    int t = threadIdx.x;
    for (int i = t; i < 512; i += 256) ws[i & 1][i >> 1] = wf[i];
    __syncthreads();
    int wv = t >> 6, ln = t & 63;
    int n = blockIdx.x * 4 + wv;
    float p0 = 0.f, p1 = 0.f;
#pragma unroll
    for (int cc = 0; cc < 4; cc++) {
        int c = ln * 4 + cc;
        float x = X[(size_t)n * 256 + c];
        p0 += x * ws[0][c];
        p1 += x * ws[1][c];
    }
#pragma unroll
    for (int off = 32; off > 0; off >>= 1) {
        p0 += __shfl_xor(p0, off, 64);
        p1 += __shfl_xor(p1, off, 64);
    }
    if (ln == 0) { al[n] = p0; ar[n] = p1; }
}

// ---------------- GAT gather: WAVE per node, readlane broadcast (no DS ops) --------
// 64 lanes/node; lane owns 2 channels (u32 = 2 bf16). Weights broadcast via
// v_readlane (wave-uniform k) -> SGPR -> v_fmac with SGPR operand.
template <int H, bool FUSE>
__launch_bounds__(256)
__global__ void gat_gather_w(const ushort* __restrict__ X, const float* __restrict__ al,
                             const float* __restrict__ ar, const int* __restrict__ offs,
                             const int* __restrict__ csr, const float* __restrict__ bias,
                             void* __restrict__ outp) {
    int t = threadIdx.x;
    int wv = t >> 6, ln = t & 63;
    int n = blockIdx.x * 4 + wv;
    int e0 = offs[n], e1 = offs[n + 1];

    float arv[H], m[H], srun[H], acc0[H], acc1[H];
#pragma unroll
    for (int h = 0; h < H; h++) {
        arv[h] = ar[n * H + h];
        m[h] = -1e30f; srun[h] = 0.f; acc0[h] = 0.f; acc1[h] = 0.f;
    }
    const ushort* Xc = X + ln * 2;

    for (int base = e0; base < e1; base += 64) {
        int cnt = e1 - base; if (cnt > 64) cnt = 64;
        bool vld = ln < cnt;
        int src = vld ? csr[base + ln] : 0;
        float wgt[H], lmx[H];
        {
            float av[H];
            if (H == 4) {
                float4 a4 = *(const float4*)(al + (size_t)src * 4);
                av[0] = a4.x; av[H > 1 ? 1 : 0] = a4.y;
                av[H > 2 ? 2 : 0] = a4.z; av[H > 3 ? 3 : 0] = a4.w;
            } else {
                av[0] = al[src];
            }
#pragma unroll
            for (int h = 0; h < H; h++) {
                float lg = av[h] + arv[h];
                lg = lg > 0.f ? lg : 0.2f * lg;
                wgt[h] = vld ? lg : -1e30f;
                lmx[h] = wgt[h];
            }
        }
        // wave max reduce
#pragma unroll
        for (int off = 32; off > 0; off >>= 1)
#pragma unroll
            for (int h = 0; h < H; h++) lmx[h] = fmaxf(lmx[h], __shfl_xor(lmx[h], off, 64));
        float ls[H];
#pragma unroll
        for (int h = 0; h < H; h++) {
            float mn = fmaxf(m[h], lmx[h]);
            float sc = __expf(m[h] - mn);
            m[h] = mn;
            srun[h] *= sc;
            acc0[h] *= sc; acc1[h] *= sc;
            wgt[h] = vld ? __expf(wgt[h] - mn) : 0.f;
            ls[h] = wgt[h];
        }
#pragma unroll
        for (int off = 32; off > 0; off >>= 1)
#pragma unroll
            for (int h = 0; h < H; h++) ls[h] += __shfl_xor(ls[h], off, 64);
#pragma unroll
        for (int h = 0; h < H; h++) srun[h] += ls[h];

        // gather: readlane broadcasts (SGPR), 4 loads in flight
        int k = 0;
        for (; k + 4 <= cnt; k += 4) {
            int s0 = __builtin_amdgcn_readlane(src, k);
            int s1 = __builtin_amdgcn_readlane(src, k + 1);
            int s2 = __builtin_amdgcn_readlane(src, k + 2);
            int s3 = __builtin_amdgcn_readlane(src, k + 3);
            unsigned u0 = *(const unsigned*)(Xc + (size_t)s0 * 128);
            unsigned u1 = *(const unsigned*)(Xc + (size_t)s1 * 128);
            unsigned u2 = *(const unsigned*)(Xc + (size_t)s2 * 128);
            unsigned u3 = *(const unsigned*)(Xc + (size_t)s3 * 128);
            float x00 = __uint_as_float(u0 << 16), x01 = __uint_as_float(u0 & 0xffff0000u);
            float x10 = __uint_as_float(u1 << 16), x11 = __uint_as_float(u1 & 0xffff0000u);
            float x20 = __uint_as_float(u2 << 16), x21 = __uint_as_float(u2 & 0xffff0000u);
            float x30 = __uint_as_float(u3 << 16), x31 = __uint_as_float(u3 & 0xffff0000u);
#pragma unroll
            for (int h = 0; h < H; h++) {
                float w0 = rlane(wgt[h], k);
                float w1 = rlane(wgt[h], k + 1);
                float w2 = rlane(wgt[h], k + 2);
                float w3 = rlane(wgt[h], k + 3);
                acc0[h] = fmaf(w0, x00, acc0[h]); acc1[h] = fmaf(w0, x01, acc1[h]);
                acc0[h] = fmaf(w1, x10, acc0[h]); acc1[h] = fmaf(w1, x11, acc1[h]);
                acc0[h] = fmaf(w2, x20, acc0[h]); acc1[h] = fmaf(w2, x21, acc1[h]);
                acc0[h] = fmaf(w3, x30, acc0[h]); acc1[h] = fmaf(w3, x31, acc1[h]);
            }
        }
        for (; k < cnt; k++) {
            int s0 = __builtin_amdgcn_readlane(src, k);
            unsigned u0 = *(const unsigned*)(Xc + (size_t)s0 * 128);
            float x00 = __uint_as_float(u0 << 16), x01 = __uint_as_float(u0 & 0xffff0000u);
#pragma unroll
            for (int h = 0; h < H; h++) {
                float w0 = rlane(wgt[h], k);
                acc0[h] = fmaf(w0, x00, acc0[h]); acc1[h] = fmaf(w0, x01, acc1[h]);
            }
        }
    }
    if (FUSE) {
        float* out = (float*)outp;
        float inv = 1.f / srun[0];
        float v0 = acc0[0] * inv + bias[ln * 2];
        float v1 = acc1[0] * inv + bias[ln * 2 + 1];
        float2 o;
        o.x = v0 > 0.f ? v0 : __expf(v0) - 1.f;
        o.y = v1 > 0.f ? v1 : __expf(v1) - 1.f;
        *(float2*)(out + (size_t)n * 128 + ln * 2) = o;
    } else {
        ushort* out = (ushort*)outp;
#pragma unroll
        for (int h = 0; h < H; h++) {
            float inv = 1.f / srun[h];
            ushort2 o;
            o.x = f2bf_rne(acc0[h] * inv);
            o.y = f2bf_rne(acc1[h] * inv);
            *(ushort2*)(out + (size_t)n * (H * 128) + h * 128 + ln * 2) = o;
        }
    }
}

// ---------------- MFMA split-bf16 GEMM ----------------
template <int ASPLIT, bool BT, int ACT, bool OUTBF, int BN>
__launch_bounds__(256)
__global__ void gemm3t(const void* __restrict__ Aptr, const float* __restrict__ B,
                       const float* __restrict__ bias, void* __restrict__ Cptr,
                       int M, int K, int lda, int ldb, int ldc, int zA, int zB, int zC) {
    constexpr int NF = BN / 32;
    __shared__ ushort Ah[128 * 64];
    __shared__ ushort Al[ASPLIT ? 128 * 64 : 64];
    __shared__ ushort Bh[64 * BN];
    __shared__ ushort Bl[64 * BN];
    int tid = threadIdx.x;
    int z = blockIdx.z;
    int bm = blockIdx.x * 128;
    int ny = blockIdx.y * BN;
    int wid = tid >> 6, ln = tid & 63;
    int wm = wid >> 1, wn = wid & 1;
    f32x4 acc[4][NF];
#pragma unroll
    for (int a = 0; a < 4; a++)
#pragma unroll
        for (int b = 0; b < NF; b++)
#pragma unroll
            for (int j = 0; j < 4; j++) acc[a][b][j] = 0.f;
    const float* Af = (const float*)Aptr;
    const ushort* Au = (const ushort*)Aptr;
    size_t abase = (size_t)z * zA;
    int bcb = z * zB + ny;

    for (int k0 = 0; k0 < K; k0 += 64) {
#pragma unroll
        for (int i = 0; i < 8; i++) {
            int idx = tid + i * 256;
            int r = idx >> 4, c4 = (idx & 15) * 4;
            int gr = bm + r;
            int ab = (r * 128 + c4 * 2) ^ ((r & 7) << 4);
            if (ASPLIT) {
                float4 v = make_float4(0.f, 0.f, 0.f, 0.f);
                if (gr < M) v = *(const float4*)(Af + abase + (size_t)gr * lda + k0 + c4);
                ushort h0, h1, h2, h3, l0, l1, l2, l3;
                split2(v.x, h0, l0); split2(v.y, h1, l1);
                split2(v.z, h2, l2); split2(v.w, h3, l3);
                *(ushort4*)((char*)Ah + ab) = make_ushort4(h0, h1, h2, h3);
                *(ushort4*)((char*)Al + ab) = make_ushort4(l0, l1, l2, l3);
            } else {
                ushort4 v = make_ushort4(0, 0, 0, 0);
                if (gr < M) v = *(const ushort4*)(Au + abase + (size_t)gr * lda + k0 + c4);
                *(ushort4*)((char*)Ah + ab) = v;
            }
        }
        if (!BT) {
#pragma unroll
            for (int i = 0; i < BN / 16; i++) {
                int idx = tid + i * 256;
                int kk = idx / (BN / 4);
                int c4 = (idx % (BN / 4)) * 4;
                float4 v = *(const float4*)(B + (size_t)(k0 + kk) * ldb + bcb + c4);
                float vv[4] = {v.x, v.y, v.z, v.w};
#pragma unroll
                for (int q = 0; q < 4; q++) {
                    int nl = c4 + q;
                    int bb = (nl * 128 + kk * 2) ^ ((nl & 7) << 4);
                    ushort h, l;
                    split2(vv[q], h, l);
                    *(ushort*)((char*)Bh + bb) = h;
                    *(ushort*)((char*)Bl + bb) = l;
                }
            }
        } else {
#pragma unroll
            for (int i = 0; i < BN / 16; i++) {
                int idx = tid + i * 256;
                int nl = idx >> 4, k4 = (idx & 15) * 4;
                float4 v = *(const float4*)(B + (size_t)(ny + nl) * ldb + k0 + k4);
                ushort h0, h1, h2, h3, l0, l1, l2, l3;
                split2(v.x, h0, l0); split2(v.y, h1, l1);
                split2(v.z, h2, l2); split2(v.w, h3, l3);
                int bb = (nl * 128 + k4 * 2) ^ ((nl & 7) << 4);
                *(ushort4*)((char*)Bh + bb) = make_ushort4(h0, h1, h2, h3);
                *(ushort4*)((char*)Bl + bb) = make_ushort4(l0, l1, l2, l3);
            }
        }
        __syncthreads();
#pragma unroll
        for (int ks = 0; ks < 2; ks++) {
            int kb = ks * 64 + (ln >> 4) * 16;
            bf16x8 ah[4], alo[ASPLIT ? 4 : 1], bh[NF], bl[NF];
#pragma unroll
            for (int mf = 0; mf < 4; mf++) {
                int r = wm * 64 + mf * 16 + (ln & 15);
                int ab = (r * 128 + kb) ^ ((r & 7) << 4);
                ah[mf] = *(bf16x8*)((char*)Ah + ab);
                if (ASPLIT) alo[mf] = *(bf16x8*)((char*)Al + ab);
            }
#pragma unroll
            for (int nf = 0; nf < NF; nf++) {
                int nl = wn * (BN / 2) + nf * 16 + (ln & 15);
                int bb = (nl * 128 + kb) ^ ((nl & 7) << 4);
                bh[nf] = *(bf16x8*)((char*)Bh + bb);
                bl[nf] = *(bf16x8*)((char*)Bl + bb);
            }
#pragma unroll
            for (int mf = 0; mf < 4; mf++)
#pragma unroll
                for (int nf = 0; nf < NF; nf++) {
                    acc[mf][nf] = __builtin_amdgcn_mfma_f32_16x16x32_bf16(ah[mf], bh[nf], acc[mf][nf], 0, 0, 0);
                    acc[mf][nf] = __builtin_amdgcn_mfma_f32_16x16x32_bf16(ah[mf], bl[nf], acc[mf][nf], 0, 0, 0);
                    if (ASPLIT)
                        acc[mf][nf] = __builtin_amdgcn_mfma_f32_16x16x32_bf16(alo[mf], bh[nf], acc[mf][nf], 0, 0, 0);
                }
        }
        __syncthreads();
    }
    float* Cf = (float*)Cptr;
    ushort* Cu = (ushort*)Cptr;
#pragma unroll
    for (int mf = 0; mf < 4; mf++)
#pragma unroll
        for (int nf = 0; nf < NF; nf++) {
            int colL = ny + wn * (BN / 2) + nf * 16 + (ln & 15);
#pragma unroll
            for (int j = 0; j < 4; j++) {
                int row = bm + wm * 64 + mf * 16 + (ln >> 4) * 4 + j;
                if (row < M) {
                    float v = acc[mf][nf][j];
                    if (ACT) {
                        v += bias[z * zC + colL];
                        v = v > 0.f ? v : (__expf(v) - 1.f);
                    }
                    size_t ci = (size_t)row * ldc + z * zC + colL;
                    if (OUTBF) Cu[ci] = f2bf_rne(v);
                    else       Cf[ci] = v;
                }
            }
        }
}

// ---------------- GRU (h0=0) + heads + SIR physics (parallelized) ----------------
__launch_bounds__(128)
__global__ void gru_heads_kernel(const float* __restrict__ gi, const float* __restrict__ b_ih,
                                 const float* __restrict__ b_hh, const float* __restrict__ cI,
                                 const float* __restrict__ cR, const float* __restrict__ Npop,
                                 const float* __restrict__ I0, const float* __restrict__ R0,
                                 const float* __restrict__ W_I, const float* __restrict__ b_I,
                                 const float* __restrict__ W_R, const float* __restrict__ b_R,
                                 const float* __restrict__ W_sir, const float* __restrict__ b_sir,
                                 float* __restrict__ out_predI, float* __restrict__ out_predR,
                                 float* __restrict__ out_phyI, float* __restrict__ out_phyR,
                                 float* __restrict__ out_h) {
    int n = blockIdx.x, t = threadIdx.x;
    __shared__ float hc[130];
    __shared__ float hp[32];
    const float* g = gi + (size_t)n * 384;
    float ir = g[t] + b_ih[t];
    float iz = g[128 + t] + b_ih[128 + t];
    float ih = g[256 + t] + b_ih[256 + t];
    float r = 1.f / (1.f + __expf(-(ir + b_hh[t])));
    float z = 1.f / (1.f + __expf(-(iz + b_hh[128 + t])));
    float xx = ih + r * b_hh[256 + t];
    xx = fminf(fmaxf(xx, -15.f), 15.f);
    float e2 = __expf(2.f * xx);
    float nn = (e2 - 1.f) / (e2 + 1.f);
    float hv = (1.f - z) * nn;   // + z*h_prev, h_prev = 0
    out_h[(size_t)n * 128 + t] = hv;
    hc[t] = hv;
    if (t == 0) { hc[128] = cI[n]; hc[129] = cR[n]; }
    __syncthreads();
    // 32 head outputs x 4 lanes each: p = t>>2, q = t&3
    {
        int p = t >> 2, q = t & 3;
        const float* Wr;
        float bb;
        if (p < 15)      { Wr = W_I + p * 130;          bb = b_I[p]; }
        else if (p < 30) { Wr = W_R + (p - 15) * 130;   bb = b_R[p - 15]; }
        else             { Wr = W_sir + (p - 30) * 130; bb = b_sir[p - 30]; }
        float s = 0.f;
        for (int d = q; d < 130; d += 4) s = fmaf(hc[d], Wr[d], s);
        s += __shfl_xor(s, 1, 64);
        s += __shfl_xor(s, 2, 64);
        if (q == 0) hp[p] = s + bb;
    }
    __syncthreads();
    if (t < 15)      out_predI[(size_t)n * 15 + t] = hp[t];
    else if (t < 30) out_predR[(size_t)n * 15 + (t - 15)] = hp[t];
    if (t < 15) {
        float alpha = 1.f / (1.f + __expf(-hp[30]));
        float beta  = 1.f / (1.f + __expf(-hp[31]));
        float Nv = Npop[n];
        float Iv = I0[n], Rv = R0[n];
        float SoN = (Nv - Iv - Rv) / Nv;
        // lane t replays the exact serial recurrence t steps (bitwise == serial)
        for (int k = 0; k < t; k++) {
            float dIv = alpha * Iv * SoN - beta * Iv;
            Iv += dIv;
        }
        float dIv = alpha * Iv * SoN - beta * Iv;
        float dRv = beta * Iv;
        out_phyI[(size_t)n * 15 + t] = dIv;
        out_phyR[(size_t)n * 15 + t] = dRv;
    }
}

extern "C" void kernel_launch(void* const* d_in, const int* in_sizes, int n_in,
                              void* d_out, int out_size, void* d_ws, size_t ws_size,
                              hipStream_t stream) {
    const float* dynamic = (const float*)d_in[0];
    const int*   ei      = (const int*)d_in[1];
    const float* cI      = (const float*)d_in[2];
    const float* cR      = (const float*)d_in[3];
    const float* Npop    = (const float*)d_in[4];
    const float* I0      = (const float*)d_in[5];
    const float* R0      = (const float*)d_in[6];
    const float* W1      = (const float*)d_in[9];
    const float* a_src1  = (const float*)d_in[10];
    const float* a_dst1  = (const float*)d_in[11];
    const float* b1      = (const float*)d_in[12];
    const float* W2      = (const float*)d_in[13];
    const float* a_src2  = (const float*)d_in[14];
    const float* a_dst2  = (const float*)d_in[15];
    const float* b2      = (const float*)d_in[16];
    const float* W_ih    = (const float*)d_in[17];
    const float* b_ih    = (const float*)d_in[19];
    const float* b_hh    = (const float*)d_in[20];
    const float* W_I     = (const float*)d_in[21];
    const float* b_I     = (const float*)d_in[22];
    const float* W_R     = (const float*)d_in[23];
    const float* b_R     = (const float*)d_in[24];
    const float* W_sir   = (const float*)d_in[25];
    const float* b_sir   = (const float*)d_in[26];
    float* out = (float*)d_out;

    // ---- workspace layout (~60 MB) ----
    int* wsi = (int*)d_ws;
    int* offs    = wsi;              // 20001 (pad 20096)
    int* csr_src = wsi + 20096;      // 660000 (pad 660096)
    int* cnt     = wsi + 680192;     // 32768
    int* sbase   = wsi + 712960;     // 32768
    float* fp = (float*)(wsi + 745728);
    float* w1f = fp; fp += 1152;     // 128*8
    float* w2f = fp; fp += 640;      // 256*2
    float* al1 = fp; fp += 80128;    // 20000*4
    float* ar1 = fp; fp += 80128;
    float* al2 = fp; fp += 20096;
    float* ar2 = fp; fp += 20096;
    ushort* dyn_bf = (ushort*)fp; fp += 1280000;   // 20000*128 bf16
    float* x1 = fp; fp += 5120000;                 // [20000][256] f32; later x2 [20000][128]
    float* R  = fp; fp += 7680000;                 // ebuf / agg_bf / xl2_bf / gi
    int2* ebuf = (int2*)R;                         // [640000] int2 (dead before agg_bf live)
    ushort* agg_bf = (ushort*)R;                   // [20000][512] bf16
    ushort* xl2_bf = (ushort*)R;                   // [20000][128] bf16 (after agg dead)
    float* gi = R;                                 // [20000][384] f32 (after xl2 dead)
    float* x2 = x1;                                // [20000][128] f32 (after x1 dead)

    // CSR build: slice histogram -> scan -> slice scatter -> bucket-local CSR
    csrA_kernel<<<NSL + 2, 256, 0, stream>>>(ei, cnt, W1, a_src1, a_dst1, w1f,
                                             W2, a_src2, a_dst2, w2f);
    csrB_kernel<<<1, 1024, 0, stream>>>(cnt, sbase);
    csrC_kernel<<<NSL + 5000, 256, 0, stream>>>(ei, sbase, ebuf, dynamic, w1f,
                                                dyn_bf, al1, ar1);
    csrD_kernel<<<NB, 256, 0, stream>>>(ebuf, sbase, offs, csr_src);

    // GAT layer 1
    gat_gather_w<4, false><<<5000, 256, 0, stream>>>(dyn_bf, al1, ar1, offs, csr_src, nullptr, agg_bf);
    gemm3t<0, false, 1, false, 64><<<dim3(157, 1, 4), 256, 0, stream>>>(
        agg_bf, W1, b1, x1, NN, 128, 512, 256, 256, 128, 64, 64);

    // GAT layer 2
    alar_apply2<<<5000, 256, 0, stream>>>(x1, w2f, al2, ar2);
    gemm3t<1, false, 0, true, 128><<<dim3(157, 1, 1), 256, 0, stream>>>(
        x1, W2, nullptr, xl2_bf, NN, 256, 256, 128, 128, 0, 0, 0);
    gat_gather_w<1, true><<<5000, 256, 0, stream>>>(xl2_bf, al2, ar2, offs, csr_src, b2, x2);

    // gi = x2 @ W_ih^T
    gemm3t<1, true, 0, false, 128><<<dim3(157, 3, 1), 256, 0, stream>>>(
        x2, W_ih, nullptr, gi, NN, 128, 128, 128, 384, 0, 0, 0);

    // GRU + prediction heads + SIR
    gru_heads_kernel<<<NN, 128, 0, stream>>>(gi, b_ih, b_hh, cI, cR, Npop, I0, R0,
                                             W_I, b_I, W_R, b_R, W_sir, b_sir,
                                             out, out + 300000, out + 600000,
                                             out + 900000, out + 1200000);
}

// Round 8
// 238.023 us; speedup vs baseline: 3.0503x; 1.0662x over previous
//
#include <hip/hip_runtime.h>

#define NN 20000
#define NE 640000
#define NET (NE + NN)   // 660000 edges incl. self-loops
#define NB 128          // dst buckets
#define RR 157          // nodes per bucket (ceil 20000/128)
#define NSL 256         // edge slices
#define ESL4 625        // int4 per slice (2500 edges)

typedef __attribute__((ext_vector_type(8))) short bf16x8;
typedef __attribute__((ext_vector_type(4))) float f32x4;

__device__ inline ushort f2bf_rne(float x) {
    unsigned u = __float_as_uint(x);
    return (ushort)((u + 0x7FFFu + ((u >> 16) & 1u)) >> 16);
}
__device__ inline void split2(float x, ushort& hi, ushort& lo) {
    unsigned u = __float_as_uint(x);
    unsigned r = (u + 0x7FFFu + ((u >> 16) & 1u)) & 0xFFFF0000u;  // RNE to bf16
    hi = (ushort)(r >> 16);
    lo = f2bf_rne(x - __uint_as_float(r));   // x - hi is exact
}
__device__ inline float rlane(float x, int k) {
    return __int_as_float(__builtin_amdgcn_readlane(__float_as_int(x), k));
}

// ---------------- csrA: per-slice bucket histogram + fold_w1 + heads pack --------
__global__ void csrA_kernel(const int* __restrict__ ei, int* __restrict__ cnt,
                            const float* __restrict__ W1, const float* __restrict__ as1,
                            const float* __restrict__ ad1, float* __restrict__ w1f,
                            const float* __restrict__ W_I, const float* __restrict__ b_I,
                            const float* __restrict__ W_R, const float* __restrict__ b_R,
                            const float* __restrict__ W_sir, const float* __restrict__ b_sir,
                            float* __restrict__ Wt, float* __restrict__ wc,
                            float* __restrict__ wb) {
    int b = blockIdx.x, t = threadIdx.x;
    if (b < NSL) {
        __shared__ int h[NB];
        if (t < NB) h[t] = 0;
        __syncthreads();
        const int4* d4 = (const int4*)(ei + NE);
        for (int i = t; i < ESL4; i += 256) {
            int4 d = d4[b * ESL4 + i];
            atomicAdd(&h[(unsigned)d.x / RR], 1);
            atomicAdd(&h[(unsigned)d.y / RR], 1);
            atomicAdd(&h[(unsigned)d.z / RR], 1);
            atomicAdd(&h[(unsigned)d.w / RR], 1);
        }
        __syncthreads();
        if (t < NB) cnt[t * NSL + b] = h[t];   // bucket-major layout
    } else if (b == NSL) {
        if (t < 128) {
            int k = t;
#pragma unroll
            for (int hh = 0; hh < 4; hh++) {
                float s1 = 0.f, s2 = 0.f;
                for (int c = 0; c < 64; c++) {
                    float w = W1[k * 256 + hh * 64 + c];
                    s1 += w * as1[hh * 64 + c];
                    s2 += w * ad1[hh * 64 + c];
                }
                w1f[k * 8 + hh] = s1;
                w1f[k * 8 + 4 + hh] = s2;
            }
        }
    } else {
        // pack Wt[128][32] = [W_I;W_R;W_sir][:, :128]^T, wc[32][2] = cols 128/129, wb
        if (t < 128) {
            for (int p = 0; p < 32; p++) {
                const float* Wr = (p < 15) ? W_I + p * 130
                                : (p < 30) ? W_R + (p - 15) * 130
                                           : W_sir + (p - 30) * 130;
                Wt[t * 32 + p] = Wr[t];
            }
        } else if (t < 160) {
            int p = t - 128;
            const float* Wr = (p < 15) ? W_I + p * 130
                            : (p < 30) ? W_R + (p - 15) * 130
                                       : W_sir + (p - 30) * 130;
            wc[p * 2] = Wr[128];
            wc[p * 2 + 1] = Wr[129];
            wb[p] = (p < 15) ? b_I[p] : (p < 30) ? b_R[p - 15] : b_sir[p - 30];
        }
    }
}

// ---------------- csrB: exclusive scan of 32768 counts (bucket-major) ----------------
__global__ void csrB_kernel(const int* __restrict__ cnt, int* __restrict__ sbase) {
    __shared__ int swsum[16], swsum2[16];
    __shared__ int s_carry;
    int t = threadIdx.x, wv = t >> 6, ln = t & 63;
    if (t == 0) s_carry = 0;
    __syncthreads();
    for (int base = 0; base < NB * NSL; base += 1024) {
        int v = cnt[base + t];
        int s = v;
#pragma unroll
        for (int o = 1; o < 64; o <<= 1) { int u = __shfl_up(s, o, 64); if (ln >= o) s += u; }
        if (ln == 63) swsum[wv] = s;
        __syncthreads();
        if (t < 16) {
            int sv = swsum[t];
#pragma unroll
            for (int o = 1; o < 16; o <<= 1) { int u = __shfl_up(sv, o, 16); if (t >= o) sv += u; }
            swsum2[t] = sv;
        }
        __syncthreads();
        sbase[base + t] = s_carry + (wv ? swsum2[wv - 1] : 0) + s - v;
        __syncthreads();
        if (t == 0) s_carry += swsum2[15];
        __syncthreads();
    }
}

// ---------------- csrC: slice scatter into ebuf + alar_cast ----------------
__global__ void csrC_kernel(const int* __restrict__ ei, const int* __restrict__ sbase,
                            int2* __restrict__ ebuf, const float* __restrict__ X,
                            const float* __restrict__ wf, ushort* __restrict__ Xbf,
                            float* __restrict__ al, float* __restrict__ ar) {
    int b = blockIdx.x, t = threadIdx.x;
    if (b < NSL) {
        __shared__ int cur[NB];
        if (t < NB) cur[t] = sbase[t * NSL + b];
        __syncthreads();
        const int4* s4 = (const int4*)ei;
        const int4* d4 = (const int4*)(ei + NE);
        for (int i = t; i < ESL4; i += 256) {
            int4 sv = s4[b * ESL4 + i];
            int4 dv = d4[b * ESL4 + i];
            int p;
            p = atomicAdd(&cur[(unsigned)dv.x / RR], 1); ebuf[p] = make_int2(sv.x, dv.x);
            p = atomicAdd(&cur[(unsigned)dv.y / RR], 1); ebuf[p] = make_int2(sv.y, dv.y);
            p = atomicAdd(&cur[(unsigned)dv.z / RR], 1); ebuf[p] = make_int2(sv.z, dv.z);
            p = atomicAdd(&cur[(unsigned)dv.w / RR], 1); ebuf[p] = make_int2(sv.w, dv.w);
        }
    } else {
        __shared__ float ws[8][128];
        for (int i = t; i < 1024; i += 256) ws[i & 7][i >> 3] = wf[i];
        __syncthreads();
        int wv = t >> 6, ln = t & 63;
        int n = (b - NSL) * 4 + wv;
        float2 xv = *(const float2*)(X + (size_t)n * 128 + ln * 2);
        ushort2 ub;
        ub.x = f2bf_rne(xv.x);
        ub.y = f2bf_rne(xv.y);
        *(ushort2*)(Xbf + (size_t)n * 128 + ln * 2) = ub;
        float p[8];
#pragma unroll
        for (int o = 0; o < 8; o++) p[o] = xv.x * ws[o][ln * 2] + xv.y * ws[o][ln * 2 + 1];
#pragma unroll
        for (int off = 32; off > 0; off >>= 1)
#pragma unroll
            for (int o = 0; o < 8; o++) p[o] += __shfl_xor(p[o], off, 64);
        if (ln == 0) {
#pragma unroll
            for (int h = 0; h < 4; h++) {
                al[n * 4 + h] = p[h];
                ar[n * 4 + h] = p[4 + h];
            }
        }
    }
}

// ---------------- csrD: per-bucket local CSR build ----------------
__global__ void csrD_kernel(const int2* __restrict__ ebuf, const int* __restrict__ sbase,
                            int* __restrict__ offs, int* __restrict__ csr_src) {
    __shared__ int hist[RR], lcur[RR];
    int b = blockIdx.x, t = threadIdx.x;
    int lo = b * RR;
    int Ra = min(RR, NN - lo);
    int e0 = sbase[b * NSL];
    int e1 = (b < NB - 1) ? sbase[(b + 1) * NSL] : NE;
    int m = e1 - e0;
    for (int i = t; i < Ra; i += 256) hist[i] = 0;
    __syncthreads();
    for (int j = t; j < m; j += 256) atomicAdd(&hist[ebuf[e0 + j].y - lo], 1);
    __syncthreads();
    if (t < 64) {
        int cbase = e0 + lo;   // earlier buckets contribute e0 edges + lo self-loops
        int carry = 0;
#pragma unroll
        for (int c = 0; c < 3; c++) {
            int i = c * 64 + t;
            int v = (i < Ra) ? hist[i] + 1 : 0;   // +1 self-loop
            int s = v;
#pragma unroll
            for (int o = 1; o < 64; o <<= 1) { int u = __shfl_up(s, o, 64); if (t >= o) s += u; }
            if (i < Ra) {
                int off = cbase + carry + s - v;
                offs[lo + i] = off;
                lcur[i] = off;
            }
            carry += __shfl(s, 63, 64);
        }
    }
    if (b == 0 && t == 255) offs[NN] = NET;
    __syncthreads();
    // self-loop in last slot of each segment
    for (int i = t; i < Ra; i += 256) csr_src[lcur[i] + hist[i]] = lo + i;
    __syncthreads();
    for (int j = t; j < m; j += 256) {
        int2 p = ebuf[e0 + j];
        int pos = atomicAdd(&lcur[p.y - lo], 1);
        csr_src[pos] = p.x;
    }
}

// ---------------- layer-2 al/ar from xl2_bf: al = xl2 . a_src2 ----------------
__launch_bounds__(256)
__global__ void alar_apply2(const ushort* __restrict__ Xbf, const float* __restrict__ a_src,
                            const float* __restrict__ a_dst, float* __restrict__ al,
                            float* __restrict__ ar) {
    __shared__ float wsa[128], wsd[128];
    int t = threadIdx.x;
    if (t < 128) { wsa[t] = a_src[t]; wsd[t] = a_dst[t]; }
    __syncthreads();
    int wv = t >> 6, ln = t & 63;
    int n = blockIdx.x * 4 + wv;
    ushort2 u = *(const ushort2*)(Xbf + (size_t)n * 128 + ln * 2);
    float x0 = __uint_as_float(((unsigned)u.x) << 16);
    float x1 = __uint_as_float(((unsigned)u.y) << 16);
    float p0 = x0 * wsa[ln * 2] + x1 * wsa[ln * 2 + 1];
    float p1 = x0 * wsd[ln * 2] + x1 * wsd[ln * 2 + 1];
#pragma unroll
    for (int off = 32; off > 0; off >>= 1) {
        p0 += __shfl_xor(p0, off, 64);
        p1 += __shfl_xor(p1, off, 64);
    }
    if (ln == 0) { al[n] = p0; ar[n] = p1; }
}

// ---------------- GAT gather: WAVE per node, readlane broadcast (no DS ops) --------
template <int H, bool FUSE>
__launch_bounds__(256)
__global__ void gat_gather_w(const ushort* __restrict__ X, const float* __restrict__ al,
                             const float* __restrict__ ar, const int* __restrict__ offs,
                             const int* __restrict__ csr, const float* __restrict__ bias,
                             void* __restrict__ outp) {
    int t = threadIdx.x;
    int wv = t >> 6, ln = t & 63;
    int n = blockIdx.x * 4 + wv;
    int e0 = offs[n], e1 = offs[n + 1];

    float arv[H], m[H], srun[H], acc0[H], acc1[H];
#pragma unroll
    for (int h = 0; h < H; h++) {
        arv[h] = ar[n * H + h];
        m[h] = -1e30f; srun[h] = 0.f; acc0[h] = 0.f; acc1[h] = 0.f;
    }
    const ushort* Xc = X + ln * 2;

    for (int base = e0; base < e1; base += 64) {
        int cnt = e1 - base; if (cnt > 64) cnt = 64;
        bool vld = ln < cnt;
        int src = vld ? csr[base + ln] : 0;
        float wgt[H], lmx[H];
        {
            float av[H];
            if (H == 4) {
                float4 a4 = *(const float4*)(al + (size_t)src * 4);
                av[0] = a4.x; av[H > 1 ? 1 : 0] = a4.y;
                av[H > 2 ? 2 : 0] = a4.z; av[H > 3 ? 3 : 0] = a4.w;
            } else {
                av[0] = al[src];
            }
#pragma unroll
            for (int h = 0; h < H; h++) {
                float lg = av[h] + arv[h];
                lg = lg > 0.f ? lg : 0.2f * lg;
                wgt[h] = vld ? lg : -1e30f;
                lmx[h] = wgt[h];
            }
        }
#pragma unroll
        for (int off = 32; off > 0; off >>= 1)
#pragma unroll
            for (int h = 0; h < H; h++) lmx[h] = fmaxf(lmx[h], __shfl_xor(lmx[h], off, 64));
        float ls[H];
#pragma unroll
        for (int h = 0; h < H; h++) {
            float mn = fmaxf(m[h], lmx[h]);
            float sc = __expf(m[h] - mn);
            m[h] = mn;
            srun[h] *= sc;
            acc0[h] *= sc; acc1[h] *= sc;
            wgt[h] = vld ? __expf(wgt[h] - mn) : 0.f;
            ls[h] = wgt[h];
        }
#pragma unroll
        for (int off = 32; off > 0; off >>= 1)
#pragma unroll
            for (int h = 0; h < H; h++) ls[h] += __shfl_xor(ls[h], off, 64);
#pragma unroll
        for (int h = 0; h < H; h++) srun[h] += ls[h];

        int k = 0;
        for (; k + 4 <= cnt; k += 4) {
            int s0 = __builtin_amdgcn_readlane(src, k);
            int s1 = __builtin_amdgcn_readlane(src, k + 1);
            int s2 = __builtin_amdgcn_readlane(src, k + 2);
            int s3 = __builtin_amdgcn_readlane(src, k + 3);
            unsigned u0 = *(const unsigned*)(Xc + (size_t)s0 * 128);
            unsigned u1 = *(const unsigned*)(Xc + (size_t)s1 * 128);
            unsigned u2 = *(const unsigned*)(Xc + (size_t)s2 * 128);
            unsigned u3 = *(const unsigned*)(Xc + (size_t)s3 * 128);
            float x00 = __uint_as_float(u0 << 16), x01 = __uint_as_float(u0 & 0xffff0000u);
            float x10 = __uint_as_float(u1 << 16), x11 = __uint_as_float(u1 & 0xffff0000u);
            float x20 = __uint_as_float(u2 << 16), x21 = __uint_as_float(u2 & 0xffff0000u);
            float x30 = __uint_as_float(u3 << 16), x31 = __uint_as_float(u3 & 0xffff0000u);
#pragma unroll
            for (int h = 0; h < H; h++) {
                float w0 = rlane(wgt[h], k);
                float w1 = rlane(wgt[h], k + 1);
                float w2 = rlane(wgt[h], k + 2);
                float w3 = rlane(wgt[h], k + 3);
                acc0[h] = fmaf(w0, x00, acc0[h]); acc1[h] = fmaf(w0, x01, acc1[h]);
                acc0[h] = fmaf(w1, x10, acc0[h]); acc1[h] = fmaf(w1, x11, acc1[h]);
                acc0[h] = fmaf(w2, x20, acc0[h]); acc1[h] = fmaf(w2, x21, acc1[h]);
                acc0[h] = fmaf(w3, x30, acc0[h]); acc1[h] = fmaf(w3, x31, acc1[h]);
            }
        }
        for (; k < cnt; k++) {
            int s0 = __builtin_amdgcn_readlane(src, k);
            unsigned u0 = *(const unsigned*)(Xc + (size_t)s0 * 128);
            float x00 = __uint_as_float(u0 << 16), x01 = __uint_as_float(u0 & 0xffff0000u);
#pragma unroll
            for (int h = 0; h < H; h++) {
                float w0 = rlane(wgt[h], k);
                acc0[h] = fmaf(w0, x00, acc0[h]); acc1[h] = fmaf(w0, x01, acc1[h]);
            }
        }
    }
    if (FUSE) {
        float* out = (float*)outp;
        float inv = 1.f / srun[0];
        float v0 = acc0[0] * inv + bias[ln * 2];
        float v1 = acc1[0] * inv + bias[ln * 2 + 1];
        float2 o;
        o.x = v0 > 0.f ? v0 : __expf(v0) - 1.f;
        o.y = v1 > 0.f ? v1 : __expf(v1) - 1.f;
        *(float2*)(out + (size_t)n * 128 + ln * 2) = o;
    } else {
        ushort* out = (ushort*)outp;
#pragma unroll
        for (int h = 0; h < H; h++) {
            float inv = 1.f / srun[h];
            ushort2 o;
            o.x = f2bf_rne(acc0[h] * inv);
            o.y = f2bf_rne(acc1[h] * inv);
            *(ushort2*)(out + (size_t)n * (H * 128) + h * 128 + ln * 2) = o;
        }
    }
}

// ---------------- MFMA split-bf16 GEMM ----------------
template <int ASPLIT, bool BT, int ACT, bool OUTBF, int BN>
__launch_bounds__(256)
__global__ void gemm3t(const void* __restrict__ Aptr, const float* __restrict__ B,
                       const float* __restrict__ bias, void* __restrict__ Cptr,
                       int M, int K, int lda, int ldb, int ldc, int zA, int zB, int zC) {
    constexpr int NF = BN / 32;
    __shared__ ushort Ah[128 * 64];
    __shared__ ushort Al[ASPLIT ? 128 * 64 : 64];
    __shared__ ushort Bh[64 * BN];
    __shared__ ushort Bl[64 * BN];
    int tid = threadIdx.x;
    int z = blockIdx.z;
    int bm = blockIdx.x * 128;
    int ny = blockIdx.y * BN;
    int wid = tid >> 6, ln = tid & 63;
    int wm = wid >> 1, wn = wid & 1;
    f32x4 acc[4][NF];
#pragma unroll
    for (int a = 0; a < 4; a++)
#pragma unroll
        for (int b = 0; b < NF; b++)
#pragma unroll
            for (int j = 0; j < 4; j++) acc[a][b][j] = 0.f;
    const float* Af = (const float*)Aptr;
    const ushort* Au = (const ushort*)Aptr;
    size_t abase = (size_t)z * zA;
    int bcb = z * zB + ny;

    for (int k0 = 0; k0 < K; k0 += 64) {
#pragma unroll
        for (int i = 0; i < 8; i++) {
            int idx = tid + i * 256;
            int r = idx >> 4, c4 = (idx & 15) * 4;
            int gr = bm + r;
            int ab = (r * 128 + c4 * 2) ^ ((r & 7) << 4);
            if (ASPLIT) {
                float4 v = make_float4(0.f, 0.f, 0.f, 0.f);
                if (gr < M) v = *(const float4*)(Af + abase + (size_t)gr * lda + k0 + c4);
                ushort h0, h1, h2, h3, l0, l1, l2, l3;
                split2(v.x, h0, l0); split2(v.y, h1, l1);
                split2(v.z, h2, l2); split2(v.w, h3, l3);
                *(ushort4*)((char*)Ah + ab) = make_ushort4(h0, h1, h2, h3);
                *(ushort4*)((char*)Al + ab) = make_ushort4(l0, l1, l2, l3);
            } else {
                ushort4 v = make_ushort4(0, 0, 0, 0);
                if (gr < M) v = *(const ushort4*)(Au + abase + (size_t)gr * lda + k0 + c4);
                *(ushort4*)((char*)Ah + ab) = v;
            }
        }
        if (!BT) {
#pragma unroll
            for (int i = 0; i < BN / 16; i++) {
                int idx = tid + i * 256;
                int kk = idx / (BN / 4);
                int c4 = (idx % (BN / 4)) * 4;
                float4 v = *(const float4*)(B + (size_t)(k0 + kk) * ldb + bcb + c4);
                float vv[4] = {v.x, v.y, v.z, v.w};
#pragma unroll
                for (int q = 0; q < 4; q++) {
                    int nl = c4 + q;
                    int bb = (nl * 128 + kk * 2) ^ ((nl & 7) << 4);
                    ushort h, l;
                    split2(vv[q], h, l);
                    *(ushort*)((char*)Bh + bb) = h;
                    *(ushort*)((char*)Bl + bb) = l;
                }
            }
        } else {
#pragma unroll
            for (int i = 0; i < BN / 16; i++) {
                int idx = tid + i * 256;
                int nl = idx >> 4, k4 = (idx & 15) * 4;
                float4 v = *(const float4*)(B + (size_t)(ny + nl) * ldb + k0 + k4);
                ushort h0, h1, h2, h3, l0, l1, l2, l3;
                split2(v.x, h0, l0); split2(v.y, h1, l1);
                split2(v.z, h2, l2); split2(v.w, h3, l3);
                int bb = (nl * 128 + k4 * 2) ^ ((nl & 7) << 4);
                *(ushort4*)((char*)Bh + bb) = make_ushort4(h0, h1, h2, h3);
                *(ushort4*)((char*)Bl + bb) = make_ushort4(l0, l1, l2, l3);
            }
        }
        __syncthreads();
#pragma unroll
        for (int ks = 0; ks < 2; ks++) {
            int kb = ks * 64 + (ln >> 4) * 16;
            bf16x8 ah[4], alo[ASPLIT ? 4 : 1], bh[NF], bl[NF];
#pragma unroll
            for (int mf = 0; mf < 4; mf++) {
                int r = wm * 64 + mf * 16 + (ln & 15);
                int ab = (r * 128 + kb) ^ ((r & 7) << 4);
                ah[mf] = *(bf16x8*)((char*)Ah + ab);
                if (ASPLIT) alo[mf] = *(bf16x8*)((char*)Al + ab);
            }
#pragma unroll
            for (int nf = 0; nf < NF; nf++) {
                int nl = wn * (BN / 2) + nf * 16 + (ln & 15);
                int bb = (nl * 128 + kb) ^ ((nl & 7) << 4);
                bh[nf] = *(bf16x8*)((char*)Bh + bb);
                bl[nf] = *(bf16x8*)((char*)Bl + bb);
            }
#pragma unroll
            for (int mf = 0; mf < 4; mf++)
#pragma unroll
                for (int nf = 0; nf < NF; nf++) {
                    acc[mf][nf] = __builtin_amdgcn_mfma_f32_16x16x32_bf16(ah[mf], bh[nf], acc[mf][nf], 0, 0, 0);
                    acc[mf][nf] = __builtin_amdgcn_mfma_f32_16x16x32_bf16(ah[mf], bl[nf], acc[mf][nf], 0, 0, 0);
                    if (ASPLIT)
                        acc[mf][nf] = __builtin_amdgcn_mfma_f32_16x16x32_bf16(alo[mf], bh[nf], acc[mf][nf], 0, 0, 0);
                }
        }
        __syncthreads();
    }
    float* Cf = (float*)Cptr;
    ushort* Cu = (ushort*)Cptr;
#pragma unroll
    for (int mf = 0; mf < 4; mf++)
#pragma unroll
        for (int nf = 0; nf < NF; nf++) {
            int colL = ny + wn * (BN / 2) + nf * 16 + (ln & 15);
#pragma unroll
            for (int j = 0; j < 4; j++) {
                int row = bm + wm * 64 + mf * 16 + (ln >> 4) * 4 + j;
                if (row < M) {
                    float v = acc[mf][nf][j];
                    if (ACT) {
                        v += bias[z * zC + colL];
                        v = v > 0.f ? v : (__expf(v) - 1.f);
                    }
                    size_t ci = (size_t)row * ldc + z * zC + colL;
                    if (OUTBF) Cu[ci] = f2bf_rne(v);
                    else       Cf[ci] = v;
                }
            }
        }
}

// ---------------- gru_h: elementwise GRU (h0=0), thread = (node, channel) --------
__launch_bounds__(256)
__global__ void gru_h_kernel(const float* __restrict__ gi, const float* __restrict__ b_ih,
                             const float* __restrict__ b_hh, float* __restrict__ out_h) {
    int idx = blockIdx.x * 256 + threadIdx.x;   // 20000*128
    int n = idx >> 7, c = idx & 127;
    const float* g = gi + (size_t)n * 384;
    float ir = g[c] + b_ih[c];
    float iz = g[128 + c] + b_ih[128 + c];
    float ih = g[256 + c] + b_ih[256 + c];
    float r = 1.f / (1.f + __expf(-(ir + b_hh[c])));
    float z = 1.f / (1.f + __expf(-(iz + b_hh[128 + c])));
    float xx = ih + r * b_hh[256 + c];
    xx = fminf(fmaxf(xx, -15.f), 15.f);
    float e2 = __expf(2.f * xx);
    float nn = (e2 - 1.f) / (e2 + 1.f);
    out_h[idx] = (1.f - z) * nn;   // + z*h_prev, h_prev = 0
}

// ---------------- sir_epi: bias/cI/cR add + SIR recurrence ----------------
__launch_bounds__(256)
__global__ void sir_epi_kernel(const float* __restrict__ G, const float* __restrict__ wc,
                               const float* __restrict__ wb, const float* __restrict__ cI,
                               const float* __restrict__ cR, const float* __restrict__ Npop,
                               const float* __restrict__ I0, const float* __restrict__ R0,
                               float* __restrict__ predI, float* __restrict__ predR,
                               float* __restrict__ phyI, float* __restrict__ phyR) {
    int idx = blockIdx.x * 256 + threadIdx.x;   // 20000*32
    int n = idx >> 5, p = idx & 31;
    float civ = cI[n], crv = cR[n];
    float v = G[(size_t)n * 32 + p] + civ * wc[p * 2] + crv * wc[p * 2 + 1] + wb[p];
    if (p < 15) {
        predI[(size_t)n * 15 + p] = v;
    } else if (p < 30) {
        predR[(size_t)n * 15 + (p - 15)] = v;
    } else if (p == 30) {
        float v31 = G[(size_t)n * 32 + 31] + civ * wc[62] + crv * wc[63] + wb[31];
        float alpha = 1.f / (1.f + __expf(-v));
        float beta  = 1.f / (1.f + __expf(-v31));
        float Nv = Npop[n];
        float Iv = I0[n], Rv = R0[n];
        float SoN = (Nv - Iv - Rv) / Nv;
        for (int st = 0; st < 15; st++) {
            float dIv = alpha * Iv * SoN - beta * Iv;
            float dRv = beta * Iv;
            phyI[(size_t)n * 15 + st] = dIv;
            phyR[(size_t)n * 15 + st] = dRv;
            Iv += dIv; Rv += dRv;
        }
    }
}

extern "C" void kernel_launch(void* const* d_in, const int* in_sizes, int n_in,
                              void* d_out, int out_size, void* d_ws, size_t ws_size,
                              hipStream_t stream) {
    const float* dynamic = (const float*)d_in[0];
    const int*   ei      = (const int*)d_in[1];
    const float* cI      = (const float*)d_in[2];
    const float* cR      = (const float*)d_in[3];
    const float* Npop    = (const float*)d_in[4];
    const float* I0      = (const float*)d_in[5];
    const float* R0      = (const float*)d_in[6];
    const float* W1      = (const float*)d_in[9];
    const float* a_src1  = (const float*)d_in[10];
    const float* a_dst1  = (const float*)d_in[11];
    const float* b1      = (const float*)d_in[12];
    const float* W2      = (const float*)d_in[13];
    const float* a_src2  = (const float*)d_in[14];
    const float* a_dst2  = (const float*)d_in[15];
    const float* b2      = (const float*)d_in[16];
    const float* W_ih    = (const float*)d_in[17];
    const float* b_ih    = (const float*)d_in[19];
    const float* b_hh    = (const float*)d_in[20];
    const float* W_I     = (const float*)d_in[21];
    const float* b_I     = (const float*)d_in[22];
    const float* W_R     = (const float*)d_in[23];
    const float* b_R     = (const float*)d_in[24];
    const float* W_sir   = (const float*)d_in[25];
    const float* b_sir   = (const float*)d_in[26];
    float* out = (float*)d_out;
    float* out_predI = out;
    float* out_predR = out + 300000;
    float* out_phyI  = out + 600000;
    float* out_phyR  = out + 900000;
    float* out_h     = out + 1200000;   // [20000][128] f32

    // ---- workspace layout (~62 MB) ----
    int* wsi = (int*)d_ws;
    int* offs    = wsi;              // 20001 (pad 20096)
    int* csr_src = wsi + 20096;      // 660000 (pad 660096)
    int* cnt     = wsi + 680192;     // 32768
    int* sbase   = wsi + 712960;     // 32768
    float* fp = (float*)(wsi + 745728);
    float* w1f = fp; fp += 1152;     // 128*8
    float* Wt  = fp; fp += 4096;     // 128*32 heads weight (transposed)
    float* wc  = fp; fp += 64;       // 32*2 (cI/cR columns)
    float* wb  = fp; fp += 64;       // 32 biases (pad)
    float* al1 = fp; fp += 80128;    // 20000*4
    float* ar1 = fp; fp += 80128;
    float* al2 = fp; fp += 20096;
    float* ar2 = fp; fp += 20096;
    ushort* dyn_bf = (ushort*)fp; fp += 1280000;   // 20000*128 bf16; later G f32 20000*32
    float* x1 = fp; fp += 5120000;                 // [20000][256] f32; later x2 [20000][128]
    float* R  = fp; fp += 7680000;                 // ebuf / agg_bf / xl2_bf / gi
    int2* ebuf = (int2*)R;                         // [640000] int2 (dead before agg_bf live)
    ushort* agg_bf = (ushort*)R;                   // [20000][512] bf16
    ushort* xl2_bf = (ushort*)R;                   // [20000][128] bf16 (after agg dead)
    float* gi = R;                                 // [20000][384] f32 (after xl2 dead)
    float* x2 = x1;                                // [20000][128] f32 (after x1 dead)
    float* G  = (float*)dyn_bf;                    // [20000][32] f32 (dyn_bf dead by then)

    // CSR build: slice histogram -> scan -> slice scatter -> bucket-local CSR
    csrA_kernel<<<NSL + 2, 256, 0, stream>>>(ei, cnt, W1, a_src1, a_dst1, w1f,
                                             W_I, b_I, W_R, b_R, W_sir, b_sir, Wt, wc, wb);
    csrB_kernel<<<1, 1024, 0, stream>>>(cnt, sbase);
    csrC_kernel<<<NSL + 5000, 256, 0, stream>>>(ei, sbase, ebuf, dynamic, w1f,
                                                dyn_bf, al1, ar1);
    csrD_kernel<<<NB, 256, 0, stream>>>(ebuf, sbase, offs, csr_src);

    // GAT layer 1
    gat_gather_w<4, false><<<5000, 256, 0, stream>>>(dyn_bf, al1, ar1, offs, csr_src, nullptr, agg_bf);
    gemm3t<0, false, 1, false, 64><<<dim3(157, 1, 4), 256, 0, stream>>>(
        agg_bf, W1, b1, x1, NN, 128, 512, 256, 256, 128, 64, 64);

    // GAT layer 2: xl2 first, then al/ar from xl2, then gather
    gemm3t<1, false, 0, true, 128><<<dim3(157, 1, 1), 256, 0, stream>>>(
        x1, W2, nullptr, xl2_bf, NN, 256, 256, 128, 128, 0, 0, 0);
    alar_apply2<<<5000, 256, 0, stream>>>(xl2_bf, a_src2, a_dst2, al2, ar2);
    gat_gather_w<1, true><<<5000, 256, 0, stream>>>(xl2_bf, al2, ar2, offs, csr_src, b2, x2);

    // gi = x2 @ W_ih^T
    gemm3t<1, true, 0, false, 128><<<dim3(157, 3, 1), 256, 0, stream>>>(
        x2, W_ih, nullptr, gi, NN, 128, 128, 128, 384, 0, 0, 0);

    // GRU elementwise -> h (direct to output)
    gru_h_kernel<<<10000, 256, 0, stream>>>(gi, b_ih, b_hh, out_h);

    // heads: G = h @ Wt  (20000x128x32 MFMA)
    gemm3t<1, false, 0, false, 32><<<dim3(157, 1, 1), 256, 0, stream>>>(
        out_h, Wt, nullptr, G, NN, 128, 128, 32, 32, 0, 0, 0);

    // epilogue: cI/cR columns + bias, SIR recurrence
    sir_epi_kernel<<<2500, 256, 0, stream>>>(G, wc, wb, cI, cR, Npop, I0, R0,
                                             out_predI, out_predR, out_phyI, out_phyR);
}